// Round 6
// baseline (181.074 us; speedup 1.0000x reference)
//
#include <hip/hip_runtime.h>
#include <hip/hip_bf16.h>

#define BB 4
#define SS 2048
#define DD 512

typedef short s16x8 __attribute__((ext_vector_type(8)));
typedef short s16x4 __attribute__((ext_vector_type(4)));
typedef float f32x4 __attribute__((ext_vector_type(4)));

__device__ __forceinline__ short f2bf(float f) {
    unsigned u = __float_as_uint(f);
    u = (u + 0x7fffu + ((u >> 16) & 1u)) >> 16;
    return (short)u;
}
__device__ __forceinline__ float bf2f(short s) {
    return __uint_as_float(((unsigned)(unsigned short)s) << 16);
}

__device__ __forceinline__ void gload_lds16(const void* g, void* l) {
    __builtin_amdgcn_global_load_lds(
        (const __attribute__((address_space(1))) void*)g,
        (__attribute__((address_space(3))) void*)l, 16, 0, 0);
}

// ---------------------------------------------------------------------------
// QK^T 256x256, BK=32, 8 waves, split-bf16 3-pass (R3-proven schedule) +
// XCD-aware block swizzle (same-batch contiguous chunks per XCD).
// int16 score output (scale 128) via LDS repack -> coalesced 16B stores.
// ---------------------------------------------------------------------------
__global__ __launch_bounds__(512, 2) void qkt256(
    const short* __restrict__ qh, const short* __restrict__ ql,
    const short* __restrict__ kh, const short* __restrict__ kl,
    short* __restrict__ outS, int nwg)
{
    __shared__ short lds[2][4][8192];  // [buf][qh,ql,kh,kl][256r x 32k] = 128 KiB

    const int tid = threadIdx.x;
    const int wave = tid >> 6, lane = tid & 63;
    // XCD swizzle: flat id -> contiguous chunk per XCD (nwg % 8 == 0)
    const int flat = blockIdx.x + 8 * blockIdx.y + 64 * blockIdx.z;
    const int w = (flat & 7) * (nwg >> 3) + (flat >> 3);
    const int bm = ((w >> 3) & 7) * 256, bn = (w & 7) * 256;
    const long z = w >> 6;
    qh += z * (long)SS * DD; ql += z * (long)SS * DD;
    kh += z * (long)SS * DD; kl += z * (long)SS * DD;
    outS += z * (long)SS * SS;

    const int wm = (wave >> 2) * 128, wn = (wave & 3) * 64;
    const int lrow = lane & 15, lk16 = (lane >> 4) * 16;

    f32x4 acc[8][4] = {};

    auto issue = [&](int buf, int arr, int k0) {
#pragma unroll
        for (int h = 0; h < 2; h++) {
            const int Lb = (h << 13) + (wave << 10) + (lane << 4);
            const int Ls = Lb ^ (((Lb >> 7) & 3) << 4);
            const int row = Ls >> 6, elem = (Ls & 63) >> 1;
            const short* s = (arr == 0) ? qh : (arr == 1) ? ql : (arr == 2) ? kh : kl;
            const int rb = (arr < 2) ? bm : bn;
            gload_lds16(s + (size_t)(rb + row) * DD + k0 + elem,
                        (char*)&lds[buf][arr][0] + Lb);
        }
    };
    auto rd = [&](int buf, int arr, int row) -> s16x8 {
        const int L = (row << 6) + lk16;
        const int Ls = L ^ (((L >> 7) & 3) << 4);
        return *(const s16x8*)((const char*)&lds[buf][arr][0] + Ls);
    };

#define QK_TILE(T, CUR, BHc, BLc, BHn, BLn, PREF)                                \
  {                                                                              \
    _Pragma("unroll")                                                            \
    for (int p = 0; p < 4; p++) {                                                \
      const s16x8 ah0 = rd(CUR, 0, wm + (p * 2 + 0) * 16 + lrow);                \
      const s16x8 al0 = rd(CUR, 1, wm + (p * 2 + 0) * 16 + lrow);                \
      const s16x8 ah1 = rd(CUR, 0, wm + (p * 2 + 1) * 16 + lrow);                \
      const s16x8 al1 = rd(CUR, 1, wm + (p * 2 + 1) * 16 + lrow);                \
      if (PREF && p == 0) { issue((CUR) ^ 1, 2, ((T) + 1) * 32);                 \
                            issue((CUR) ^ 1, 0, ((T) + 1) * 32); }               \
      if (PREF && p == 1) { issue((CUR) ^ 1, 3, ((T) + 1) * 32);                 \
                            issue((CUR) ^ 1, 1, ((T) + 1) * 32); }               \
      if (PREF && p == 3) {                                                      \
        __builtin_amdgcn_sched_barrier(0); /* pin A-reads before B-reads */      \
        _Pragma("unroll")                                                        \
        for (int n = 0; n < 4; n++) {                                            \
          BHn[n] = rd((CUR) ^ 1, 2, wn + n * 16 + lrow);                         \
          BLn[n] = rd((CUR) ^ 1, 3, wn + n * 16 + lrow);                         \
        }                                                                        \
      }                                                                          \
      __builtin_amdgcn_s_barrier();                                              \
      if (PREF && p == 3) { asm volatile("s_waitcnt lgkmcnt(8)" ::: "memory"); } \
      else                { asm volatile("s_waitcnt lgkmcnt(0)" ::: "memory"); } \
      __builtin_amdgcn_sched_barrier(0);                                         \
      __builtin_amdgcn_s_setprio(1);                                             \
      _Pragma("unroll")                                                          \
      for (int pass = 0; pass < 3; pass++) {                                     \
        _Pragma("unroll")                                                        \
        for (int q = 0; q < 2; q++) {                                            \
          const s16x8 af = (pass == 2) ? (q ? al1 : al0) : (q ? ah1 : ah0);      \
          _Pragma("unroll")                                                      \
          for (int n = 0; n < 4; n++) {                                          \
            const s16x8 bf = (pass == 1) ? BLc[n] : BHc[n];                      \
            acc[p * 2 + q][n] =                                                  \
                __builtin_amdgcn_mfma_f32_16x16x32_bf16(af, bf, acc[p * 2 + q][n], 0, 0, 0); \
          }                                                                      \
        }                                                                        \
      }                                                                          \
      __builtin_amdgcn_s_setprio(0);                                             \
      if (PREF && p == 2) { asm volatile("s_waitcnt vmcnt(2)" ::: "memory");     \
                            __builtin_amdgcn_sched_barrier(0); }                 \
      if (PREF && p == 3) { asm volatile("s_waitcnt vmcnt(0)" ::: "memory");     \
                            __builtin_amdgcn_sched_barrier(0); }                 \
      __builtin_amdgcn_s_barrier();                                              \
    }                                                                            \
  }

    issue(0, 2, 0); issue(0, 0, 0); issue(0, 3, 0); issue(0, 1, 0);
    asm volatile("s_waitcnt vmcnt(0)" ::: "memory");
    __builtin_amdgcn_s_barrier();
    s16x8 bE_h[4], bE_l[4], bO_h[4], bO_l[4];
#pragma unroll
    for (int n = 0; n < 4; n++) {
        bE_h[n] = rd(0, 2, wn + n * 16 + lrow);
        bE_l[n] = rd(0, 3, wn + n * 16 + lrow);
    }

    for (int t = 0; t < 14; t += 2) {
        QK_TILE(t,     0, bE_h, bE_l, bO_h, bO_l, 1);
        QK_TILE(t + 1, 1, bO_h, bO_l, bE_h, bE_l, 1);
    }
    QK_TILE(14, 0, bE_h, bE_l, bO_h, bO_l, 1);
    QK_TILE(15, 1, bO_h, bO_l, bE_h, bE_l, 0);
#undef QK_TILE

    // int16 epilogue via LDS repack, then coalesced 16B/lane stores.
    __syncthreads();
    short* ebuf = &lds[0][0][0];  // 128 KiB = [256][256] int16
#pragma unroll
    for (int m = 0; m < 8; m++) {
#pragma unroll
        for (int n = 0; n < 4; n++) {
#pragma unroll
            for (int j = 0; j < 4; j++) {
                const int rl = wm + m * 16 + (lane >> 4) * 4 + j;
                const int cl = wn + n * 16 + lrow;
                const int pcb = (cl >> 3) ^ ((rl & 3) << 1);
                ebuf[rl * 256 + pcb * 8 + (cl & 7)] =
                    (short)__float2int_rn(acc[m][n][j] * 128.0f);
            }
        }
    }
    __syncthreads();
#pragma unroll
    for (int it = 0; it < 16; it++) {
        const int u = it * 512 + tid;
        const int R = u >> 5, cb = u & 31;
        const int pcb = cb ^ ((R & 3) << 1);
        const s16x8 val = *(const s16x8*)&ebuf[R * 256 + pcb * 8];
        *(s16x8*)&outS[(size_t)(bm + R) * SS + bn + cb * 8] = val;
    }
}

// ---------------------------------------------------------------------------
// Fused softmax + PV. Block = 64 Q-rows x 256 V-cols, full K=2048.
// Pre-pass: online max+sumexp over int16 scores (8 lanes/row, shfl combine).
// Main loop: P = exp(s/128 - m)*inv staged bf16 into padded LDS (VALU path),
// V staged via swizzled global_load_lds. 8 waves (2M x 4N), dbuf, out fp32.
// ---------------------------------------------------------------------------
__global__ __launch_bounds__(512, 2) void pv_fused(
    const short* __restrict__ S, const short* __restrict__ vt,
    float* __restrict__ out, int nwg)
{
    __shared__ short Vbuf[2][256 * 32];   // 16 KiB each, qkt-style swizzle
    __shared__ short Pbuf[2][64 * 40];    // 80 B rows (pad 8): aligned b128
    __shared__ float mrow[64], sinv[64];

    const int tid = threadIdx.x;
    const int wave = tid >> 6, lane = tid & 63;
    const int flat = blockIdx.x + 2 * blockIdx.y + 64 * blockIdx.z;
    const int w = (flat & 7) * (nwg >> 3) + (flat >> 3);
    const int bx = w & 1, by = (w >> 1) & 31;
    const long z = w >> 6;
    const int r0 = by * 64, c0 = bx * 256;
    const short* sP = S + z * (long)SS * SS;
    const short* vP = vt + (z << 20);
    float* oP = out + z * (long)SS * DD;

    const int lrow = lane & 15, lk16 = (lane >> 4) * 16;
    const int wm = (wave >> 2) * 32, wn = (wave & 3) * 64;

    // ---- pre-pass: row max + sumexp (8 lanes per row) ----
    {
        const int row = tid >> 3, lane8 = tid & 7;
        const short* sr = sP + (size_t)(r0 + row) * SS;
        float m_t = -3e38f, s_t = 0.f;
#pragma unroll 4
        for (int k = 0; k < 32; k++) {
            const s16x8 ch = *(const s16x8*)&sr[(lane8 + k * 8) * 8];
            float v[8];
#pragma unroll
            for (int j = 0; j < 8; j++) v[j] = (float)(int)ch[j] * 0.0078125f;
            float mx = v[0];
#pragma unroll
            for (int j = 1; j < 8; j++) mx = fmaxf(mx, v[j]);
            const float mn = fmaxf(m_t, mx);
            float acc8 = s_t * __expf(m_t - mn);
#pragma unroll
            for (int j = 0; j < 8; j++) acc8 += __expf(v[j] - mn);
            m_t = mn; s_t = acc8;
        }
#pragma unroll
        for (int off = 1; off < 8; off <<= 1) {
            const float mo = __shfl_xor(m_t, off), so = __shfl_xor(s_t, off);
            const float mn = fmaxf(m_t, mo);
            s_t = s_t * __expf(m_t - mn) + so * __expf(mo - mn);
            m_t = mn;
        }
        if (lane8 == 0) { mrow[row] = m_t; sinv[row] = 1.0f / s_t; }
    }
    __syncthreads();

    // per-thread P-staging constants (thread owns one row slice)
    const int prow = tid >> 3, pc4 = (tid & 7) * 4;
    const float pm = mrow[prow], pi = sinv[prow];
    const short* srowP = sP + (size_t)(r0 + prow) * SS + pc4;

    auto issueV = [&](int buf, int k0) {
#pragma unroll
        for (int h = 0; h < 2; h++) {
            const int Lb = (h << 13) + (wave << 10) + (lane << 4);
            const int Ls = Lb ^ (((Lb >> 7) & 3) << 4);
            const int row = Ls >> 6, elem = (Ls & 63) >> 1;
            gload_lds16(vP + ((size_t)(c0 + row) << 11) + k0 + elem,
                        (char*)&Vbuf[buf][0] + Lb);
        }
    };
    auto rdV = [&](int buf, int row) -> s16x8 {
        const int L = (row << 6) + lk16;
        const int Ls = L ^ (((L >> 7) & 3) << 4);
        return *(const s16x8*)((const char*)&Vbuf[buf][0] + Ls);
    };
    auto expWrite = [&](int buf, s16x4 sr4) {
        s16x4 o;
#pragma unroll
        for (int j = 0; j < 4; j++)
            o[j] = f2bf(__expf((float)(int)sr4[j] * 0.0078125f - pm) * pi);
        *(s16x4*)((char*)&Pbuf[buf][0] + prow * 80 + pc4 * 2) = o;
    };

    f32x4 acc[2][4] = {};

    // prologue: stage tile 0
    issueV(0, 0);
    s16x4 sr4 = *(const s16x4*)&srowP[0];
    expWrite(0, sr4);
    __syncthreads();

    for (int t = 0; t < 64; t++) {
        const int cur = t & 1, nxt = cur ^ 1;
        if (t < 63) {
            issueV(nxt, (t + 1) * 32);
            sr4 = *(const s16x4*)&srowP[(t + 1) * 32];
        }
        s16x8 a[2], b[4];
#pragma unroll
        for (int m = 0; m < 2; m++)
            a[m] = *(const s16x8*)((const char*)&Pbuf[cur][0] +
                                   (wm + m * 16 + lrow) * 80 + lk16);
#pragma unroll
        for (int n = 0; n < 4; n++)
            b[n] = rdV(cur, wn + n * 16 + lrow);
#pragma unroll
        for (int m = 0; m < 2; m++)
#pragma unroll
            for (int n = 0; n < 4; n++)
                acc[m][n] = __builtin_amdgcn_mfma_f32_16x16x32_bf16(a[m], b[n], acc[m][n], 0, 0, 0);
        if (t < 63) expWrite(nxt, sr4);
        __syncthreads();
    }

#pragma unroll
    for (int m = 0; m < 2; m++) {
#pragma unroll
        for (int n = 0; n < 4; n++) {
#pragma unroll
            for (int j = 0; j < 4; j++) {
                const int row = r0 + wm + m * 16 + (lane >> 4) * 4 + j;
                const int col = c0 + wn + n * 16 + lrow;
                oP[(size_t)row * DD + col] = acc[m][n][j];
            }
        }
    }
}

// ---------------------------------------------------------------------------
// m97-structure 128x128 GEMM for projections. OMODE: 2=bf16 transposed Vt out;
// 3=merged Q|K split out.
// ---------------------------------------------------------------------------
template<int PLANES, int OMODE, bool BIAS>
__global__ __launch_bounds__(256, 2) void gemm_bt(
    const short* __restrict__ A0, const short* __restrict__ A1,
    const short* __restrict__ B0, const short* __restrict__ B1,
    const float* __restrict__ bias, const float* __restrict__ bias2,
    float* __restrict__ outF, short* __restrict__ outH, short* __restrict__ outL,
    short* __restrict__ outH2, short* __restrict__ outL2,
    int M, int N, int K, long zStrideA, long zStrideB, long zStrideO)
{
    __shared__ short As[PLANES][128 * 64];
    __shared__ short Bs[PLANES][128 * 64];
    __shared__ short cbuf[(OMODE == 2) ? 128 * 128 : 1];

    const int tid = threadIdx.x;
    const int wave = tid >> 6, lane = tid & 63;
    const int bm = blockIdx.y * 128, bn = blockIdx.x * 128;
    const long z = blockIdx.z;

    A0 += z * zStrideA;
    B0 += z * zStrideB;
    if (PLANES == 2) { A1 += z * zStrideA; B1 += z * zStrideB; }

    f32x4 acc[4][4] = {};
    const int wm = (wave >> 1) * 64, wn = (wave & 1) * 64;
    const int lrow = lane & 15, lk = (lane >> 4) * 8;
    const int Lbase = (wave * 64 + lane) * 16;

    for (int k0 = 0; k0 < K; k0 += 64) {
        if (k0) __syncthreads();
#pragma unroll
        for (int r = 0; r < 4; r++) {
            const int L = Lbase + r * 4096;
            const int row = L >> 7;
            const int col = (L & 127) >> 1;
            gload_lds16(A0 + (size_t)(bm + row) * K + k0 + col, (char*)&As[0][0] + L);
            gload_lds16(B0 + (size_t)(bn + row) * K + k0 + col, (char*)&Bs[0][0] + L);
            if (PLANES == 2) {
                gload_lds16(A1 + (size_t)(bm + row) * K + k0 + col, (char*)&As[1][0] + L);
                gload_lds16(B1 + (size_t)(bn + row) * K + k0 + col, (char*)&Bs[1][0] + L);
            }
        }
        __syncthreads();

#pragma unroll
        for (int kk = 0; kk < 64; kk += 32) {
            s16x8 ah[4], bh[4], al[4], bl[4];
#pragma unroll
            for (int m = 0; m < 4; m++)
                ah[m] = *(const s16x8*)&As[0][(wm + m * 16 + lrow) * 64 + kk + lk];
#pragma unroll
            for (int n = 0; n < 4; n++)
                bh[n] = *(const s16x8*)&Bs[0][(wn + n * 16 + lrow) * 64 + kk + lk];
            if (PLANES == 2) {
#pragma unroll
                for (int m = 0; m < 4; m++)
                    al[m] = *(const s16x8*)&As[1][(wm + m * 16 + lrow) * 64 + kk + lk];
#pragma unroll
                for (int n = 0; n < 4; n++)
                    bl[n] = *(const s16x8*)&Bs[1][(wn + n * 16 + lrow) * 64 + kk + lk];
            }
#pragma unroll
            for (int m = 0; m < 4; m++) {
#pragma unroll
                for (int n = 0; n < 4; n++) {
                    acc[m][n] = __builtin_amdgcn_mfma_f32_16x16x32_bf16(ah[m], bh[n], acc[m][n], 0, 0, 0);
                    if (PLANES == 2) {
                        acc[m][n] = __builtin_amdgcn_mfma_f32_16x16x32_bf16(ah[m], bl[n], acc[m][n], 0, 0, 0);
                        acc[m][n] = __builtin_amdgcn_mfma_f32_16x16x32_bf16(al[m], bh[n], acc[m][n], 0, 0, 0);
                    }
                }
            }
        }
    }

    const bool isK2 = (OMODE == 3) && (bn >= 512);
#pragma unroll
    for (int m = 0; m < 4; m++) {
#pragma unroll
        for (int n = 0; n < 4; n++) {
#pragma unroll
            for (int j = 0; j < 4; j++) {
                const int row = bm + wm + m * 16 + (lane >> 4) * 4 + j;
                const int col = bn + wn + n * 16 + lrow;
                float v = acc[m][n][j];
                if (OMODE == 0) {
                    if (BIAS) v += bias[col];
                    (outF + z * zStrideO)[(size_t)row * N + col] = v;
                } else if (OMODE == 3) {
                    v += (isK2 ? bias2 : bias)[col & 511];
                    const short h = f2bf(v);
                    const short l = f2bf(v - bf2f(h));
                    const size_t idx = (size_t)row * DD + (col & 511);
                    (isK2 ? outH2 : outH)[idx] = h;
                    (isK2 ? outL2 : outL)[idx] = l;
                } else {  // OMODE 2
                    if (BIAS) v += bias[col];
                    const int cl = wn + n * 16 + lrow;
                    const int rl = wm + m * 16 + (lane >> 4) * 4 + j;
                    cbuf[cl * 128 + (rl ^ ((cl & 7) << 3))] = f2bf(v);
                }
            }
        }
    }
    if (OMODE == 2) {
        __syncthreads();
        const int b = bm >> 11;
        const int s0 = bm & 2047;
#pragma unroll
        for (int it = 0; it < 8; it++) {
            const int idx = it * 256 + tid;
            const int dd = idx >> 4;
            const int c8 = (idx & 15) * 8;
            const s16x8 val = *(const s16x8*)&cbuf[dd * 128 + (c8 ^ ((dd & 7) << 3))];
            *(s16x8*)&outH[((size_t)b << 20) + ((size_t)(bn + dd) << 11) + s0 + c8] = val;
        }
    }
}

__global__ __launch_bounds__(256) void cast_x_split(
    const float* __restrict__ x, short* __restrict__ xh, short* __restrict__ xl, int n4)
{
    const int i = blockIdx.x * 256 + threadIdx.x;
    if (i >= n4) return;
    const float4 v = ((const float4*)x)[i];
    const float vv[4] = {v.x, v.y, v.z, v.w};
    s16x4 h, l;
#pragma unroll
    for (int j = 0; j < 4; j++) {
        const short hh = f2bf(vv[j]);
        h[j] = hh;
        l[j] = f2bf(vv[j] - bf2f(hh));
    }
    ((s16x4*)xh)[i] = h;
    ((s16x4*)xl)[i] = l;
}

__global__ __launch_bounds__(256) void cast_w_split(
    const float* __restrict__ wq, const float* __restrict__ wk, const float* __restrict__ wv,
    short* __restrict__ wth, short* __restrict__ wtl)
{
    const int t = blockIdx.x * 256 + threadIdx.x;
    const int w = blockIdx.y;
    const float* src = (w == 0) ? wq : ((w == 1) ? wk : wv);
    const int k = t >> 9, n = t & 511;
    const float v = src[t];
    const short h = f2bf(v);
    const short l = f2bf(v - bf2f(h));
    const size_t dst = ((size_t)w << 18) + ((size_t)n << 9) + k;
    wth[dst] = h;
    wtl[dst] = l;
}

extern "C" void kernel_launch(void* const* d_in, const int* in_sizes, int n_in,
                              void* d_out, int out_size, void* d_ws, size_t ws_size,
                              hipStream_t stream)
{
    const float* x  = (const float*)d_in[0];
    const float* Wq = (const float*)d_in[1];
    const float* Wk = (const float*)d_in[2];
    const float* Wv = (const float*)d_in[3];
    const float* bq = (const float*)d_in[4];
    const float* bk = (const float*)d_in[5];
    const float* bv = (const float*)d_in[6];
    float* out = (float*)d_out;

    const size_t MK = (size_t)BB * SS * DD;
    char* ws = (char*)d_ws;
    short* xh  = (short*)ws; ws += MK * 2;
    short* xl  = (short*)ws; ws += MK * 2;
    short* wth = (short*)ws; ws += 3ull * DD * DD * 2;
    short* wtl = (short*)ws; ws += 3ull * DD * DD * 2;
    short* qh  = (short*)ws; ws += MK * 2;
    short* ql  = (short*)ws; ws += MK * 2;
    short* kh  = (short*)ws; ws += MK * 2;
    short* kl  = (short*)ws; ws += MK * 2;
    short* vt  = (short*)ws; ws += MK * 2;
    const size_t fixed = (size_t)(ws - (char*)d_ws);

    int g = 4;
    while (g > 0 && fixed + (size_t)g * ((size_t)SS * SS * 2) > ws_size)
        g >>= 1;
    if (g == 0) return;
    short* sc = (short*)ws;

    cast_x_split<<<dim3((unsigned)(MK / 4 / 256)), 256, 0, stream>>>(x, xh, xl, (int)(MK / 4));
    cast_w_split<<<dim3(1024, 3), 256, 0, stream>>>(Wq, Wk, Wv, wth, wtl);

    gemm_bt<2, 3, true><<<dim3(8, 64, 1), 256, 0, stream>>>(
        xh, xl, wth, wtl, bq, bk,
        nullptr, qh, ql, kh, kl, BB * SS, DD, DD, 0, 0, 0);
    gemm_bt<1, 2, true><<<dim3(4, 64, 1), 256, 0, stream>>>(
        xh, nullptr, wth + 2 * DD * DD, nullptr, bv, nullptr,
        nullptr, vt, nullptr, nullptr, nullptr, BB * SS, DD, DD, 0, 0, 0);

    for (int b0 = 0; b0 < BB; b0 += g) {
        const int gg = (b0 + g <= BB) ? g : (BB - b0);
        qkt256<<<dim3(8, 8, gg), 512, 0, stream>>>(
            qh + (size_t)b0 * SS * DD, ql + (size_t)b0 * SS * DD,
            kh + (size_t)b0 * SS * DD, kl + (size_t)b0 * SS * DD, sc, 64 * gg);
        pv_fused<<<dim3(2, 32, gg), 512, 0, stream>>>(
            sc, vt + ((size_t)b0 << 20), out + (size_t)b0 * SS * DD, 64 * gg);
    }
}

// Round 7
// 160.303 us; speedup vs baseline: 1.1296x; 1.1296x over previous
//
#include <hip/hip_runtime.h>
#include <hip/hip_bf16.h>
#include <hip/hip_fp16.h>

#define BB 4
#define SS 2048
#define DD 512

typedef short s16x8 __attribute__((ext_vector_type(8)));
typedef short s16x4 __attribute__((ext_vector_type(4)));
typedef float f32x4 __attribute__((ext_vector_type(4)));
typedef _Float16 f16x8 __attribute__((ext_vector_type(8)));

__device__ __forceinline__ short f2bf(float f) {
    unsigned u = __float_as_uint(f);
    u = (u + 0x7fffu + ((u >> 16) & 1u)) >> 16;
    return (short)u;
}
__device__ __forceinline__ float bf2f(short s) {
    return __uint_as_float(((unsigned)(unsigned short)s) << 16);
}
__device__ __forceinline__ short f2h(float f) {
    const _Float16 h = (_Float16)f;
    union { _Float16 h; short s; } u; u.h = h; return u.s;
}
__device__ __forceinline__ float h2f(short s) {
    union { short s; _Float16 h; } u; u.s = s; return (float)u.h;
}
__device__ __forceinline__ f16x8 as_h(s16x8 v) {
    union { s16x8 s; f16x8 h; } u; u.s = v; return u.h;
}

__device__ __forceinline__ void gload_lds16(const void* g, void* l) {
    __builtin_amdgcn_global_load_lds(
        (const __attribute__((address_space(1))) void*)g,
        (__attribute__((address_space(3))) void*)l, 16, 0, 0);
}

// ---------------------------------------------------------------------------
// QK^T 256x256, BK=32, 8 waves, fp16 2-pass (Qh*K + Ql*K; K single fp16
// plane, Q split hi/lo fp16). R3-proven schedule + XCD swizzle.
// int16 score out (scale 128) via LDS repack -> coalesced 16B stores.
// Staging planes: arr 0=qh, 1=ql, 2=kf. 96KB staging inside 128KB union.
// ---------------------------------------------------------------------------
__global__ __launch_bounds__(512, 2) void qkt256(
    const short* __restrict__ qh, const short* __restrict__ ql,
    const short* __restrict__ kf, short* __restrict__ outS, int nwg)
{
    __shared__ short lds[65536];  // 128 KiB: [2][3][8192] staging, reused as ebuf

    const int tid = threadIdx.x;
    const int wave = tid >> 6, lane = tid & 63;
    const int flat = blockIdx.x + 8 * blockIdx.y + 64 * blockIdx.z;
    const int w = (flat & 7) * (nwg >> 3) + (flat >> 3);
    const int bm = ((w >> 3) & 7) * 256, bn = (w & 7) * 256;
    const long z = w >> 6;
    qh += z * (long)SS * DD; ql += z * (long)SS * DD; kf += z * (long)SS * DD;
    outS += z * (long)SS * SS;

    const int wm = (wave >> 2) * 128, wn = (wave & 3) * 64;
    const int lrow = lane & 15, lk16 = (lane >> 4) * 16;

    f32x4 acc[8][4] = {};

    auto base = [&](int buf, int arr) -> short* { return &lds[(buf * 3 + arr) * 8192]; };
    auto issue = [&](int buf, int arr, int k0) {
#pragma unroll
        for (int h = 0; h < 2; h++) {
            const int Lb = (h << 13) + (wave << 10) + (lane << 4);
            const int Ls = Lb ^ (((Lb >> 7) & 3) << 4);
            const int row = Ls >> 6, elem = (Ls & 63) >> 1;
            const short* s = (arr == 0) ? qh : (arr == 1) ? ql : kf;
            const int rb = (arr < 2) ? bm : bn;
            gload_lds16(s + (size_t)(rb + row) * DD + k0 + elem,
                        (char*)base(buf, arr) + Lb);
        }
    };
    auto rd = [&](int buf, int arr, int row) -> s16x8 {
        const int L = (row << 6) + lk16;
        const int Ls = L ^ (((L >> 7) & 3) << 4);
        return *(const s16x8*)((const char*)base(buf, arr) + Ls);
    };

// staging order per tile: kf,qh (p0: 4 loads), ql (p1: 2 loads)
// vmcnt(4)@p2-end -> kf landed (gates B-next reads at p3, after barrier)
// vmcnt(0)@p3-end -> all landed (gates next tile's A reads)
#define QK_TILE(T, CUR, Bc, Bn, PREF)                                            \
  {                                                                              \
    _Pragma("unroll")                                                            \
    for (int p = 0; p < 4; p++) {                                                \
      const s16x8 ah0 = rd(CUR, 0, wm + (p * 2 + 0) * 16 + lrow);                \
      const s16x8 al0 = rd(CUR, 1, wm + (p * 2 + 0) * 16 + lrow);                \
      const s16x8 ah1 = rd(CUR, 0, wm + (p * 2 + 1) * 16 + lrow);                \
      const s16x8 al1 = rd(CUR, 1, wm + (p * 2 + 1) * 16 + lrow);                \
      if (PREF && p == 0) { issue((CUR) ^ 1, 2, ((T) + 1) * 32);                 \
                            issue((CUR) ^ 1, 0, ((T) + 1) * 32); }               \
      if (PREF && p == 1) { issue((CUR) ^ 1, 1, ((T) + 1) * 32); }               \
      if (PREF && p == 3) {                                                      \
        __builtin_amdgcn_sched_barrier(0); /* pin A-reads before B-reads */      \
        _Pragma("unroll")                                                        \
        for (int n = 0; n < 4; n++) {                                            \
          Bn[n] = rd((CUR) ^ 1, 2, wn + n * 16 + lrow);                          \
        }                                                                        \
      }                                                                          \
      __builtin_amdgcn_s_barrier();                                              \
      if (PREF && p == 3) { asm volatile("s_waitcnt lgkmcnt(4)" ::: "memory"); } \
      else                { asm volatile("s_waitcnt lgkmcnt(0)" ::: "memory"); } \
      __builtin_amdgcn_sched_barrier(0);                                         \
      __builtin_amdgcn_s_setprio(1);                                             \
      _Pragma("unroll")                                                          \
      for (int pass = 0; pass < 2; pass++) {                                     \
        _Pragma("unroll")                                                        \
        for (int q = 0; q < 2; q++) {                                            \
          const s16x8 af = pass ? (q ? al1 : al0) : (q ? ah1 : ah0);             \
          _Pragma("unroll")                                                      \
          for (int n = 0; n < 4; n++) {                                          \
            acc[p * 2 + q][n] = __builtin_amdgcn_mfma_f32_16x16x32_f16(          \
                as_h(af), as_h(Bc[n]), acc[p * 2 + q][n], 0, 0, 0);              \
          }                                                                      \
        }                                                                        \
      }                                                                          \
      __builtin_amdgcn_s_setprio(0);                                             \
      if (PREF && p == 2) { asm volatile("s_waitcnt vmcnt(4)" ::: "memory");     \
                            __builtin_amdgcn_sched_barrier(0); }                 \
      if (PREF && p == 3) { asm volatile("s_waitcnt vmcnt(0)" ::: "memory");     \
                            __builtin_amdgcn_sched_barrier(0); }                 \
      __builtin_amdgcn_s_barrier();                                              \
    }                                                                            \
  }

    issue(0, 2, 0); issue(0, 0, 0); issue(0, 1, 0);
    asm volatile("s_waitcnt vmcnt(0)" ::: "memory");
    __builtin_amdgcn_s_barrier();
    s16x8 bE[4], bO[4];
#pragma unroll
    for (int n = 0; n < 4; n++) bE[n] = rd(0, 2, wn + n * 16 + lrow);

    for (int t = 0; t < 14; t += 2) {
        QK_TILE(t,     0, bE, bO, 1);
        QK_TILE(t + 1, 1, bO, bE, 1);
    }
    QK_TILE(14, 0, bE, bO, 1);
    QK_TILE(15, 1, bO, bE, 0);
#undef QK_TILE

    // int16 epilogue via LDS repack, then coalesced 16B/lane stores.
    __syncthreads();
    short* ebuf = &lds[0];  // 128 KiB = [256][256] int16
#pragma unroll
    for (int m = 0; m < 8; m++) {
#pragma unroll
        for (int n = 0; n < 4; n++) {
#pragma unroll
            for (int j = 0; j < 4; j++) {
                const int rl = wm + m * 16 + (lane >> 4) * 4 + j;
                const int cl = wn + n * 16 + lrow;
                const int pcb = (cl >> 3) ^ ((rl & 3) << 1);
                ebuf[rl * 256 + pcb * 8 + (cl & 7)] =
                    (short)__float2int_rn(acc[m][n][j] * 128.0f);
            }
        }
    }
    __syncthreads();
#pragma unroll
    for (int it = 0; it < 16; it++) {
        const int u = it * 512 + tid;
        const int R = u >> 5, cb = u & 31;
        const int pcb = cb ^ ((R & 3) << 1);
        const s16x8 val = *(const s16x8*)&ebuf[R * 256 + pcb * 8];
        *(s16x8*)&outS[(size_t)(bm + R) * SS + bn + cb * 8] = val;
    }
}

// ---------------------------------------------------------------------------
// m97-structure 128x128 GEMM. OMODE: 0=fp32 out (PV); 2=bf16 transposed Vt
// out; 3=merged Q|K out (Q: fp16 hi/lo split -> outH/outL; K: fp16 -> outH2).
// ---------------------------------------------------------------------------
template<int PLANES, int OMODE, bool BIAS>
__global__ __launch_bounds__(256, 2) void gemm_bt(
    const short* __restrict__ A0, const short* __restrict__ A1,
    const short* __restrict__ B0, const short* __restrict__ B1,
    const float* __restrict__ bias, const float* __restrict__ bias2,
    float* __restrict__ outF, short* __restrict__ outH, short* __restrict__ outL,
    short* __restrict__ outH2,
    int M, int N, int K, long zStrideA, long zStrideB, long zStrideO)
{
    __shared__ short As[PLANES][128 * 64];
    __shared__ short Bs[PLANES][128 * 64];
    __shared__ short cbuf[(OMODE == 2) ? 128 * 128 : 1];

    const int tid = threadIdx.x;
    const int wave = tid >> 6, lane = tid & 63;
    const int bm = blockIdx.y * 128, bn = blockIdx.x * 128;
    const long z = blockIdx.z;

    A0 += z * zStrideA;
    B0 += z * zStrideB;
    if (PLANES == 2) { A1 += z * zStrideA; B1 += z * zStrideB; }

    f32x4 acc[4][4] = {};
    const int wm = (wave >> 1) * 64, wn = (wave & 1) * 64;
    const int lrow = lane & 15, lk = (lane >> 4) * 8;
    const int Lbase = (wave * 64 + lane) * 16;

    for (int k0 = 0; k0 < K; k0 += 64) {
        if (k0) __syncthreads();
#pragma unroll
        for (int r = 0; r < 4; r++) {
            const int L = Lbase + r * 4096;
            const int row = L >> 7;
            const int col = (L & 127) >> 1;
            gload_lds16(A0 + (size_t)(bm + row) * K + k0 + col, (char*)&As[0][0] + L);
            gload_lds16(B0 + (size_t)(bn + row) * K + k0 + col, (char*)&Bs[0][0] + L);
            if (PLANES == 2) {
                gload_lds16(A1 + (size_t)(bm + row) * K + k0 + col, (char*)&As[1][0] + L);
                gload_lds16(B1 + (size_t)(bn + row) * K + k0 + col, (char*)&Bs[1][0] + L);
            }
        }
        __syncthreads();

#pragma unroll
        for (int kk = 0; kk < 64; kk += 32) {
            s16x8 ah[4], bh[4], al[4], bl[4];
#pragma unroll
            for (int m = 0; m < 4; m++)
                ah[m] = *(const s16x8*)&As[0][(wm + m * 16 + lrow) * 64 + kk + lk];
#pragma unroll
            for (int n = 0; n < 4; n++)
                bh[n] = *(const s16x8*)&Bs[0][(wn + n * 16 + lrow) * 64 + kk + lk];
            if (PLANES == 2) {
#pragma unroll
                for (int m = 0; m < 4; m++)
                    al[m] = *(const s16x8*)&As[1][(wm + m * 16 + lrow) * 64 + kk + lk];
#pragma unroll
                for (int n = 0; n < 4; n++)
                    bl[n] = *(const s16x8*)&Bs[1][(wn + n * 16 + lrow) * 64 + kk + lk];
            }
#pragma unroll
            for (int m = 0; m < 4; m++) {
#pragma unroll
                for (int n = 0; n < 4; n++) {
                    acc[m][n] = __builtin_amdgcn_mfma_f32_16x16x32_bf16(ah[m], bh[n], acc[m][n], 0, 0, 0);
                    if (PLANES == 2) {
                        acc[m][n] = __builtin_amdgcn_mfma_f32_16x16x32_bf16(ah[m], bl[n], acc[m][n], 0, 0, 0);
                        acc[m][n] = __builtin_amdgcn_mfma_f32_16x16x32_bf16(al[m], bh[n], acc[m][n], 0, 0, 0);
                    }
                }
            }
        }
    }

    const bool isK2 = (OMODE == 3) && (bn >= 512);
#pragma unroll
    for (int m = 0; m < 4; m++) {
#pragma unroll
        for (int n = 0; n < 4; n++) {
#pragma unroll
            for (int j = 0; j < 4; j++) {
                const int row = bm + wm + m * 16 + (lane >> 4) * 4 + j;
                const int col = bn + wn + n * 16 + lrow;
                float v = acc[m][n][j];
                if (OMODE == 0) {
                    if (BIAS) v += bias[col];
                    (outF + z * zStrideO)[(size_t)row * N + col] = v;
                } else if (OMODE == 3) {
                    v += (isK2 ? bias2 : bias)[col & 511];
                    const size_t idx = (size_t)row * DD + (col & 511);
                    if (isK2) {
                        outH2[idx] = f2h(v);          // K: single fp16
                    } else {
                        const short h = f2h(v);       // Q: fp16 hi/lo split
                        outH[idx] = h;
                        outL[idx] = f2h(v - h2f(h));
                    }
                } else {  // OMODE 2
                    if (BIAS) v += bias[col];
                    const int cl = wn + n * 16 + lrow;
                    const int rl = wm + m * 16 + (lane >> 4) * 4 + j;
                    cbuf[cl * 128 + (rl ^ ((cl & 7) << 3))] = f2bf(v);
                }
            }
        }
    }
    if (OMODE == 2) {
        __syncthreads();
        const int b = bm >> 11;
        const int s0 = bm & 2047;
#pragma unroll
        for (int it = 0; it < 8; it++) {
            const int idx = it * 256 + tid;
            const int dd = idx >> 4;
            const int c8 = (idx & 15) * 8;
            const s16x8 val = *(const s16x8*)&cbuf[dd * 128 + (c8 ^ ((dd & 7) << 3))];
            *(s16x8*)&outH[((size_t)b << 20) + ((size_t)(bn + dd) << 11) + s0 + c8] = val;
        }
    }
}

__global__ __launch_bounds__(256) void cast_x_split(
    const float* __restrict__ x, short* __restrict__ xh, short* __restrict__ xl, int n4)
{
    const int i = blockIdx.x * 256 + threadIdx.x;
    if (i >= n4) return;
    const float4 v = ((const float4*)x)[i];
    const float vv[4] = {v.x, v.y, v.z, v.w};
    s16x4 h, l;
#pragma unroll
    for (int j = 0; j < 4; j++) {
        const short hh = f2bf(vv[j]);
        h[j] = hh;
        l[j] = f2bf(vv[j] - bf2f(hh));
    }
    ((s16x4*)xh)[i] = h;
    ((s16x4*)xl)[i] = l;
}

__global__ __launch_bounds__(256) void cast_w_split(
    const float* __restrict__ wq, const float* __restrict__ wk, const float* __restrict__ wv,
    short* __restrict__ wth, short* __restrict__ wtl)
{
    const int t = blockIdx.x * 256 + threadIdx.x;
    const int w = blockIdx.y;
    const float* src = (w == 0) ? wq : ((w == 1) ? wk : wv);
    const int k = t >> 9, n = t & 511;
    const float v = src[t];
    const short h = f2bf(v);
    const short l = f2bf(v - bf2f(h));
    const size_t dst = ((size_t)w << 18) + ((size_t)n << 9) + k;
    wth[dst] = h;
    wtl[dst] = l;
}

// softmax over int16 scores (scale 1/128), bf16 P out
__global__ __launch_bounds__(256) void softmax_rows(
    const short* __restrict__ S, short* __restrict__ P)
{
    const int row = blockIdx.x;
    const long z = blockIdx.y;
    const short* s = S + z * (long)SS * SS + (long)row * SS;
    short* p = P + z * (long)SS * SS + (long)row * SS;
    const int tid = threadIdx.x;

    const s16x8 raw = ((const s16x8*)s)[tid];
    float v[8];
#pragma unroll
    for (int j = 0; j < 8; j++) v[j] = (float)(int)raw[j] * 0.0078125f;

    float m = v[0];
#pragma unroll
    for (int j = 1; j < 8; j++) m = fmaxf(m, v[j]);
#pragma unroll
    for (int off = 32; off >= 1; off >>= 1) m = fmaxf(m, __shfl_xor(m, off));
    __shared__ float redm[4], reds[4];
    if ((tid & 63) == 0) redm[tid >> 6] = m;
    __syncthreads();
    m = fmaxf(fmaxf(redm[0], redm[1]), fmaxf(redm[2], redm[3]));

    float e[8], sum = 0.f;
#pragma unroll
    for (int j = 0; j < 8; j++) { e[j] = __expf(v[j] - m); sum += e[j]; }
#pragma unroll
    for (int off = 32; off >= 1; off >>= 1) sum += __shfl_xor(sum, off);
    if ((tid & 63) == 0) reds[tid >> 6] = sum;
    __syncthreads();
    sum = reds[0] + reds[1] + reds[2] + reds[3];
    const float inv = 1.0f / sum;

    s16x8 o;
#pragma unroll
    for (int j = 0; j < 8; j++) o[j] = f2bf(e[j] * inv);
    ((s16x8*)p)[tid] = o;
}

extern "C" void kernel_launch(void* const* d_in, const int* in_sizes, int n_in,
                              void* d_out, int out_size, void* d_ws, size_t ws_size,
                              hipStream_t stream)
{
    const float* x  = (const float*)d_in[0];
    const float* Wq = (const float*)d_in[1];
    const float* Wk = (const float*)d_in[2];
    const float* Wv = (const float*)d_in[3];
    const float* bq = (const float*)d_in[4];
    const float* bk = (const float*)d_in[5];
    const float* bv = (const float*)d_in[6];
    float* out = (float*)d_out;

    const size_t MK = (size_t)BB * SS * DD;
    char* ws = (char*)d_ws;
    short* xh  = (short*)ws; ws += MK * 2;
    short* xl  = (short*)ws; ws += MK * 2;
    short* wth = (short*)ws; ws += 3ull * DD * DD * 2;
    short* wtl = (short*)ws; ws += 3ull * DD * DD * 2;
    short* qhp = (short*)ws; ws += MK * 2;
    short* qlp = (short*)ws; ws += MK * 2;
    short* kfp = (short*)ws; ws += MK * 2;
    short* vt  = (short*)ws; ws += MK * 2;
    const size_t fixed = (size_t)(ws - (char*)d_ws);

    int g = 4;
    while (g > 0 && fixed + (size_t)g * ((size_t)SS * SS * 2 + (size_t)SS * SS * 2) > ws_size)
        g >>= 1;
    if (g == 0) return;
    short* sc = (short*)ws;
    short* P  = (short*)(ws + (size_t)g * SS * SS * 2);

    cast_x_split<<<dim3((unsigned)(MK / 4 / 256)), 256, 0, stream>>>(x, xh, xl, (int)(MK / 4));
    cast_w_split<<<dim3(1024, 3), 256, 0, stream>>>(Wq, Wk, Wv, wth, wtl);

    // merged Q|K projection: Q -> fp16 hi/lo (qhp/qlp), K -> single fp16 (kfp)
    gemm_bt<2, 3, true><<<dim3(8, 64, 1), 256, 0, stream>>>(
        xh, xl, wth, wtl, bq, bk,
        nullptr, qhp, qlp, kfp, BB * SS, DD, DD, 0, 0, 0);
    // V projection with transposed coalesced epilogue (bf16 Vt)
    gemm_bt<1, 2, true><<<dim3(4, 64, 1), 256, 0, stream>>>(
        xh, nullptr, wth + 2 * DD * DD, nullptr, bv, nullptr,
        nullptr, vt, nullptr, nullptr, BB * SS, DD, DD, 0, 0, 0);

    for (int b0 = 0; b0 < BB; b0 += g) {
        const int gg = (b0 + g <= BB) ? g : (BB - b0);
        qkt256<<<dim3(8, 8, gg), 512, 0, stream>>>(
            qhp + (size_t)b0 * SS * DD, qlp + (size_t)b0 * SS * DD,
            kfp + (size_t)b0 * SS * DD, sc, 64 * gg);
        softmax_rows<<<dim3(SS, gg), 256, 0, stream>>>(sc, P);
        gemm_bt<1, 0, false><<<dim3(4, 16, gg), 256, 0, stream>>>(
            P, nullptr, vt + ((size_t)b0 << 20), nullptr, nullptr, nullptr,
            out + (size_t)b0 * SS * DD, nullptr, nullptr, nullptr, SS, DD, SS,
            (long)SS * SS, (long)DD * SS, (long)SS * DD);
    }
}

// Round 8
// 148.148 us; speedup vs baseline: 1.2222x; 1.0820x over previous
//
#include <hip/hip_runtime.h>
#include <hip/hip_bf16.h>
#include <hip/hip_fp16.h>

#define BB 4
#define SS 2048
#define DD 512

typedef short s16x8 __attribute__((ext_vector_type(8)));
typedef short s16x4 __attribute__((ext_vector_type(4)));
typedef float f32x4 __attribute__((ext_vector_type(4)));
typedef _Float16 f16x8 __attribute__((ext_vector_type(8)));

__device__ __forceinline__ short f2bf(float f) {
    unsigned u = __float_as_uint(f);
    u = (u + 0x7fffu + ((u >> 16) & 1u)) >> 16;
    return (short)u;
}
__device__ __forceinline__ float bf2f(short s) {
    return __uint_as_float(((unsigned)(unsigned short)s) << 16);
}
__device__ __forceinline__ short f2h(float f) {
    const _Float16 h = (_Float16)f;
    union { _Float16 h; short s; } u; u.h = h; return u.s;
}
__device__ __forceinline__ float h2f(short s) {
    union { short s; _Float16 h; } u; u.s = s; return (float)u.h;
}
__device__ __forceinline__ f16x8 as_h(s16x8 v) {
    union { s16x8 s; f16x8 h; } u; u.s = v; return u.h;
}

__device__ __forceinline__ void gload_lds16(const void* g, void* l) {
    __builtin_amdgcn_global_load_lds(
        (const __attribute__((address_space(1))) void*)g,
        (__attribute__((address_space(3))) void*)l, 16, 0, 0);
}

// ---------------------------------------------------------------------------
// QK^T 256x256, BK=32, 8 waves, fp16 2-pass (Qh*K + Ql*K). R3-proven
// schedule + XCD swizzle. int16 score out via LDS repack.
// ---------------------------------------------------------------------------
__global__ __launch_bounds__(512, 2) void qkt256(
    const short* __restrict__ qh, const short* __restrict__ ql,
    const short* __restrict__ kf, short* __restrict__ outS, int nwg)
{
    __shared__ short lds[65536];  // 128 KiB: [2][3][8192] staging, reused as ebuf

    const int tid = threadIdx.x;
    const int wave = tid >> 6, lane = tid & 63;
    const int flat = blockIdx.x + 8 * blockIdx.y + 64 * blockIdx.z;
    const int w = (flat & 7) * (nwg >> 3) + (flat >> 3);
    const int bm = ((w >> 3) & 7) * 256, bn = (w & 7) * 256;
    const long z = w >> 6;
    qh += z * (long)SS * DD; ql += z * (long)SS * DD; kf += z * (long)SS * DD;
    outS += z * (long)SS * SS;

    const int wm = (wave >> 2) * 128, wn = (wave & 3) * 64;
    const int lrow = lane & 15, lk16 = (lane >> 4) * 16;

    f32x4 acc[8][4] = {};

    auto base = [&](int buf, int arr) -> short* { return &lds[(buf * 3 + arr) * 8192]; };
    auto issue = [&](int buf, int arr, int k0) {
#pragma unroll
        for (int h = 0; h < 2; h++) {
            const int Lb = (h << 13) + (wave << 10) + (lane << 4);
            const int Ls = Lb ^ (((Lb >> 7) & 3) << 4);
            const int row = Ls >> 6, elem = (Ls & 63) >> 1;
            const short* s = (arr == 0) ? qh : (arr == 1) ? ql : kf;
            const int rb = (arr < 2) ? bm : bn;
            gload_lds16(s + (size_t)(rb + row) * DD + k0 + elem,
                        (char*)base(buf, arr) + Lb);
        }
    };
    auto rd = [&](int buf, int arr, int row) -> s16x8 {
        const int L = (row << 6) + lk16;
        const int Ls = L ^ (((L >> 7) & 3) << 4);
        return *(const s16x8*)((const char*)base(buf, arr) + Ls);
    };

#define QK_TILE(T, CUR, Bc, Bn, PREF)                                            \
  {                                                                              \
    _Pragma("unroll")                                                            \
    for (int p = 0; p < 4; p++) {                                                \
      const s16x8 ah0 = rd(CUR, 0, wm + (p * 2 + 0) * 16 + lrow);                \
      const s16x8 al0 = rd(CUR, 1, wm + (p * 2 + 0) * 16 + lrow);                \
      const s16x8 ah1 = rd(CUR, 0, wm + (p * 2 + 1) * 16 + lrow);                \
      const s16x8 al1 = rd(CUR, 1, wm + (p * 2 + 1) * 16 + lrow);                \
      if (PREF && p == 0) { issue((CUR) ^ 1, 2, ((T) + 1) * 32);                 \
                            issue((CUR) ^ 1, 0, ((T) + 1) * 32); }               \
      if (PREF && p == 1) { issue((CUR) ^ 1, 1, ((T) + 1) * 32); }               \
      if (PREF && p == 3) {                                                      \
        __builtin_amdgcn_sched_barrier(0); /* pin A-reads before B-reads */      \
        _Pragma("unroll")                                                        \
        for (int n = 0; n < 4; n++) {                                            \
          Bn[n] = rd((CUR) ^ 1, 2, wn + n * 16 + lrow);                          \
        }                                                                        \
      }                                                                          \
      __builtin_amdgcn_s_barrier();                                              \
      if (PREF && p == 3) { asm volatile("s_waitcnt lgkmcnt(4)" ::: "memory"); } \
      else                { asm volatile("s_waitcnt lgkmcnt(0)" ::: "memory"); } \
      __builtin_amdgcn_sched_barrier(0);                                         \
      __builtin_amdgcn_s_setprio(1);                                             \
      _Pragma("unroll")                                                          \
      for (int pass = 0; pass < 2; pass++) {                                     \
        _Pragma("unroll")                                                        \
        for (int q = 0; q < 2; q++) {                                            \
          const s16x8 af = pass ? (q ? al1 : al0) : (q ? ah1 : ah0);             \
          _Pragma("unroll")                                                      \
          for (int n = 0; n < 4; n++) {                                          \
            acc[p * 2 + q][n] = __builtin_amdgcn_mfma_f32_16x16x32_f16(          \
                as_h(af), as_h(Bc[n]), acc[p * 2 + q][n], 0, 0, 0);              \
          }                                                                      \
        }                                                                        \
      }                                                                          \
      __builtin_amdgcn_s_setprio(0);                                             \
      if (PREF && p == 2) { asm volatile("s_waitcnt vmcnt(4)" ::: "memory");     \
                            __builtin_amdgcn_sched_barrier(0); }                 \
      if (PREF && p == 3) { asm volatile("s_waitcnt vmcnt(0)" ::: "memory");     \
                            __builtin_amdgcn_sched_barrier(0); }                 \
      __builtin_amdgcn_s_barrier();                                              \
    }                                                                            \
  }

    issue(0, 2, 0); issue(0, 0, 0); issue(0, 1, 0);
    asm volatile("s_waitcnt vmcnt(0)" ::: "memory");
    __builtin_amdgcn_s_barrier();
    s16x8 bE[4], bO[4];
#pragma unroll
    for (int n = 0; n < 4; n++) bE[n] = rd(0, 2, wn + n * 16 + lrow);

    for (int t = 0; t < 14; t += 2) {
        QK_TILE(t,     0, bE, bO, 1);
        QK_TILE(t + 1, 1, bO, bE, 1);
    }
    QK_TILE(14, 0, bE, bO, 1);
    QK_TILE(15, 1, bO, bE, 0);
#undef QK_TILE

    __syncthreads();
    short* ebuf = &lds[0];  // 128 KiB = [256][256] int16
#pragma unroll
    for (int m = 0; m < 8; m++) {
#pragma unroll
        for (int n = 0; n < 4; n++) {
#pragma unroll
            for (int j = 0; j < 4; j++) {
                const int rl = wm + m * 16 + (lane >> 4) * 4 + j;
                const int cl = wn + n * 16 + lrow;
                const int pcb = (cl >> 3) ^ ((rl & 3) << 1);
                ebuf[rl * 256 + pcb * 8 + (cl & 7)] =
                    (short)__float2int_rn(acc[m][n][j] * 128.0f);
            }
        }
    }
    __syncthreads();
#pragma unroll
    for (int it = 0; it < 16; it++) {
        const int u = it * 512 + tid;
        const int R = u >> 5, cb = u & 31;
        const int pcb = cb ^ ((R & 3) << 1);
        const s16x8 val = *(const s16x8*)&ebuf[R * 256 + pcb * 8];
        *(s16x8*)&outS[(size_t)(bm + R) * SS + bn + cb * 8] = val;
    }
}

// ---------------------------------------------------------------------------
// m97-structure BMx128 GEMM with 3-bit XOR LDS swizzle (16-way -> 2-way bank
// conflicts; linear gload dest + inverse-swizzled source + swizzled reads).
// OMODE: 0=fp32 out (PV, BM=64 for 2 blocks/CU); 2=bf16 transposed Vt out;
// 3=merged Q|K out (Q: fp16 hi/lo -> outH/outL; K: fp16 -> outH2).
// ---------------------------------------------------------------------------
template<int PLANES, int OMODE, bool BIAS, int BM>
__global__ __launch_bounds__(256, 2) void gemm_bt(
    const short* __restrict__ A0, const short* __restrict__ A1,
    const short* __restrict__ B0, const short* __restrict__ B1,
    const float* __restrict__ bias, const float* __restrict__ bias2,
    float* __restrict__ outF, short* __restrict__ outH, short* __restrict__ outL,
    short* __restrict__ outH2,
    int M, int N, int K, long zStrideA, long zStrideB, long zStrideO)
{
    constexpr int MF = BM / 32;  // M-frags per wave
    __shared__ short As[PLANES][BM * 64];
    __shared__ short Bs[PLANES][128 * 64];
    __shared__ short cbuf[(OMODE == 2) ? 128 * 128 : 1];

    const int tid = threadIdx.x;
    const int wave = tid >> 6, lane = tid & 63;
    const int bm = blockIdx.y * BM, bn = blockIdx.x * 128;
    const long z = blockIdx.z;

    A0 += z * zStrideA;
    B0 += z * zStrideB;
    if (PLANES == 2) { A1 += z * zStrideA; B1 += z * zStrideB; }

    f32x4 acc[MF][4] = {};
    const int wm = (wave >> 1) * (MF * 16), wn = (wave & 1) * 64;
    const int lrow = lane & 15, lk = (lane >> 4) * 8;

    auto swz = [](int L) { return L ^ (((L >> 7) & 7) << 4); };

    for (int k0 = 0; k0 < K; k0 += 64) {
        if (k0) __syncthreads();
#pragma unroll
        for (int r = 0; r < BM / 32; r++) {
            const int L = tid * 16 + r * 4096;
            const int Ls = swz(L);
            const int row = Ls >> 7, col = (Ls & 127) >> 1;
            gload_lds16(A0 + (size_t)(bm + row) * K + k0 + col, (char*)&As[0][0] + L);
            if (PLANES == 2)
                gload_lds16(A1 + (size_t)(bm + row) * K + k0 + col, (char*)&As[1][0] + L);
        }
#pragma unroll
        for (int r = 0; r < 4; r++) {
            const int L = tid * 16 + r * 4096;
            const int Ls = swz(L);
            const int row = Ls >> 7, col = (Ls & 127) >> 1;
            gload_lds16(B0 + (size_t)(bn + row) * K + k0 + col, (char*)&Bs[0][0] + L);
            if (PLANES == 2)
                gload_lds16(B1 + (size_t)(bn + row) * K + k0 + col, (char*)&Bs[1][0] + L);
        }
        __syncthreads();

#pragma unroll
        for (int kk = 0; kk < 64; kk += 32) {
            s16x8 ah[MF], bh[4], al[MF], bl[4];
#pragma unroll
            for (int m = 0; m < MF; m++)
                ah[m] = *(const s16x8*)((const char*)&As[0][0] +
                        swz(((wm + m * 16 + lrow) * 64 + kk + lk) * 2));
#pragma unroll
            for (int n = 0; n < 4; n++)
                bh[n] = *(const s16x8*)((const char*)&Bs[0][0] +
                        swz(((wn + n * 16 + lrow) * 64 + kk + lk) * 2));
            if (PLANES == 2) {
#pragma unroll
                for (int m = 0; m < MF; m++)
                    al[m] = *(const s16x8*)((const char*)&As[1][0] +
                            swz(((wm + m * 16 + lrow) * 64 + kk + lk) * 2));
#pragma unroll
                for (int n = 0; n < 4; n++)
                    bl[n] = *(const s16x8*)((const char*)&Bs[1][0] +
                            swz(((wn + n * 16 + lrow) * 64 + kk + lk) * 2));
            }
#pragma unroll
            for (int m = 0; m < MF; m++) {
#pragma unroll
                for (int n = 0; n < 4; n++) {
                    acc[m][n] = __builtin_amdgcn_mfma_f32_16x16x32_bf16(ah[m], bh[n], acc[m][n], 0, 0, 0);
                    if (PLANES == 2) {
                        acc[m][n] = __builtin_amdgcn_mfma_f32_16x16x32_bf16(ah[m], bl[n], acc[m][n], 0, 0, 0);
                        acc[m][n] = __builtin_amdgcn_mfma_f32_16x16x32_bf16(al[m], bh[n], acc[m][n], 0, 0, 0);
                    }
                }
            }
        }
    }

    const bool isK2 = (OMODE == 3) && (bn >= 512);
#pragma unroll
    for (int m = 0; m < MF; m++) {
#pragma unroll
        for (int n = 0; n < 4; n++) {
#pragma unroll
            for (int j = 0; j < 4; j++) {
                const int row = bm + wm + m * 16 + (lane >> 4) * 4 + j;
                const int col = bn + wn + n * 16 + lrow;
                float v = acc[m][n][j];
                if (OMODE == 0) {
                    if (BIAS) v += bias[col];
                    (outF + z * zStrideO)[(size_t)row * N + col] = v;
                } else if (OMODE == 3) {
                    v += (isK2 ? bias2 : bias)[col & 511];
                    const size_t idx = (size_t)row * DD + (col & 511);
                    if (isK2) {
                        outH2[idx] = f2h(v);          // K: single fp16
                    } else {
                        const short h = f2h(v);       // Q: fp16 hi/lo split
                        outH[idx] = h;
                        outL[idx] = f2h(v - h2f(h));
                    }
                } else {  // OMODE 2
                    if (BIAS) v += bias[col];
                    const int cl = wn + n * 16 + lrow;
                    const int rl = wm + m * 16 + (lane >> 4) * 4 + j;
                    cbuf[cl * 128 + (rl ^ ((cl & 7) << 3))] = f2bf(v);
                }
            }
        }
    }
    if (OMODE == 2) {
        __syncthreads();
        const int b = bm >> 11;
        const int s0 = bm & 2047;
#pragma unroll
        for (int it = 0; it < 8; it++) {
            const int idx = it * 256 + tid;
            const int dd = idx >> 4;
            const int c8 = (idx & 15) * 8;
            const s16x8 val = *(const s16x8*)&cbuf[dd * 128 + (c8 ^ ((dd & 7) << 3))];
            *(s16x8*)&outH[((size_t)b << 20) + ((size_t)(bn + dd) << 11) + s0 + c8] = val;
        }
    }
}

__global__ __launch_bounds__(256) void cast_x_split(
    const float* __restrict__ x, short* __restrict__ xh, short* __restrict__ xl, int n4)
{
    const int i = blockIdx.x * 256 + threadIdx.x;
    if (i >= n4) return;
    const float4 v = ((const float4*)x)[i];
    const float vv[4] = {v.x, v.y, v.z, v.w};
    s16x4 h, l;
#pragma unroll
    for (int j = 0; j < 4; j++) {
        const short hh = f2bf(vv[j]);
        h[j] = hh;
        l[j] = f2bf(vv[j] - bf2f(hh));
    }
    ((s16x4*)xh)[i] = h;
    ((s16x4*)xl)[i] = l;
}

__global__ __launch_bounds__(256) void cast_w_split(
    const float* __restrict__ wq, const float* __restrict__ wk, const float* __restrict__ wv,
    short* __restrict__ wth, short* __restrict__ wtl)
{
    const int t = blockIdx.x * 256 + threadIdx.x;
    const int w = blockIdx.y;
    const float* src = (w == 0) ? wq : ((w == 1) ? wk : wv);
    const int k = t >> 9, n = t & 511;
    const float v = src[t];
    const short h = f2bf(v);
    const short l = f2bf(v - bf2f(h));
    const size_t dst = ((size_t)w << 18) + ((size_t)n << 9) + k;
    wth[dst] = h;
    wtl[dst] = l;
}

// softmax over int16 scores (scale 1/128), bf16 P out
__global__ __launch_bounds__(256) void softmax_rows(
    const short* __restrict__ S, short* __restrict__ P)
{
    const int row = blockIdx.x;
    const long z = blockIdx.y;
    const short* s = S + z * (long)SS * SS + (long)row * SS;
    short* p = P + z * (long)SS * SS + (long)row * SS;
    const int tid = threadIdx.x;

    const s16x8 raw = ((const s16x8*)s)[tid];
    float v[8];
#pragma unroll
    for (int j = 0; j < 8; j++) v[j] = (float)(int)raw[j] * 0.0078125f;

    float m = v[0];
#pragma unroll
    for (int j = 1; j < 8; j++) m = fmaxf(m, v[j]);
#pragma unroll
    for (int off = 32; off >= 1; off >>= 1) m = fmaxf(m, __shfl_xor(m, off));
    __shared__ float redm[4], reds[4];
    if ((tid & 63) == 0) redm[tid >> 6] = m;
    __syncthreads();
    m = fmaxf(fmaxf(redm[0], redm[1]), fmaxf(redm[2], redm[3]));

    float e[8], sum = 0.f;
#pragma unroll
    for (int j = 0; j < 8; j++) { e[j] = __expf(v[j] - m); sum += e[j]; }
#pragma unroll
    for (int off = 32; off >= 1; off >>= 1) sum += __shfl_xor(sum, off);
    if ((tid & 63) == 0) reds[tid >> 6] = sum;
    __syncthreads();
    sum = reds[0] + reds[1] + reds[2] + reds[3];
    const float inv = 1.0f / sum;

    s16x8 o;
#pragma unroll
    for (int j = 0; j < 8; j++) o[j] = f2bf(e[j] * inv);
    ((s16x8*)p)[tid] = o;
}

extern "C" void kernel_launch(void* const* d_in, const int* in_sizes, int n_in,
                              void* d_out, int out_size, void* d_ws, size_t ws_size,
                              hipStream_t stream)
{
    const float* x  = (const float*)d_in[0];
    const float* Wq = (const float*)d_in[1];
    const float* Wk = (const float*)d_in[2];
    const float* Wv = (const float*)d_in[3];
    const float* bq = (const float*)d_in[4];
    const float* bk = (const float*)d_in[5];
    const float* bv = (const float*)d_in[6];
    float* out = (float*)d_out;

    const size_t MK = (size_t)BB * SS * DD;
    char* ws = (char*)d_ws;
    short* xh  = (short*)ws; ws += MK * 2;
    short* xl  = (short*)ws; ws += MK * 2;
    short* wth = (short*)ws; ws += 3ull * DD * DD * 2;
    short* wtl = (short*)ws; ws += 3ull * DD * DD * 2;
    short* qhp = (short*)ws; ws += MK * 2;
    short* qlp = (short*)ws; ws += MK * 2;
    short* kfp = (short*)ws; ws += MK * 2;
    short* vt  = (short*)ws; ws += MK * 2;
    const size_t fixed = (size_t)(ws - (char*)d_ws);

    int g = 4;
    while (g > 0 && fixed + (size_t)g * ((size_t)SS * SS * 2 + (size_t)SS * SS * 2) > ws_size)
        g >>= 1;
    if (g == 0) return;
    short* sc = (short*)ws;
    short* P  = (short*)(ws + (size_t)g * SS * SS * 2);

    cast_x_split<<<dim3((unsigned)(MK / 4 / 256)), 256, 0, stream>>>(x, xh, xl, (int)(MK / 4));
    cast_w_split<<<dim3(1024, 3), 256, 0, stream>>>(Wq, Wk, Wv, wth, wtl);

    // merged Q|K projection: Q -> fp16 hi/lo (qhp/qlp), K -> single fp16 (kfp)
    gemm_bt<2, 3, true, 128><<<dim3(8, 64, 1), 256, 0, stream>>>(
        xh, xl, wth, wtl, bq, bk,
        nullptr, qhp, qlp, kfp, BB * SS, DD, DD, 0, 0, 0);
    // V projection with transposed coalesced epilogue (bf16 Vt)
    gemm_bt<1, 2, true, 128><<<dim3(4, 64, 1), 256, 0, stream>>>(
        xh, nullptr, wth + 2 * DD * DD, nullptr, bv, nullptr,
        nullptr, vt, nullptr, nullptr, BB * SS, DD, DD, 0, 0, 0);

    for (int b0 = 0; b0 < BB; b0 += g) {
        const int gg = (b0 + g <= BB) ? g : (BB - b0);
        qkt256<<<dim3(8, 8, gg), 512, 0, stream>>>(
            qhp + (size_t)b0 * SS * DD, qlp + (size_t)b0 * SS * DD,
            kfp + (size_t)b0 * SS * DD, sc, 64 * gg);
        softmax_rows<<<dim3(SS, gg), 256, 0, stream>>>(sc, P);
        // PV: BM=64 tile -> 512 blocks (2 blocks/CU)
        gemm_bt<1, 0, false, 64><<<dim3(4, 32, gg), 256, 0, stream>>>(
            P, nullptr, vt + ((size_t)b0 << 20), nullptr, nullptr, nullptr,
            out + (size_t)b0 * SS * DD, nullptr, nullptr, nullptr, SS, DD, SS,
            (long)SS * SS, (long)DD * SS, (long)SS * DD);
    }
}

// Round 9
// 133.145 us; speedup vs baseline: 1.3600x; 1.1127x over previous
//
#include <hip/hip_runtime.h>
#include <hip/hip_bf16.h>
#include <hip/hip_fp16.h>

#define BB 4
#define SS 2048
#define DD 512

typedef short s16x8 __attribute__((ext_vector_type(8)));
typedef short s16x4 __attribute__((ext_vector_type(4)));
typedef float f32x4 __attribute__((ext_vector_type(4)));
typedef _Float16 f16x8 __attribute__((ext_vector_type(8)));

__device__ __forceinline__ short f2bf(float f) {
    unsigned u = __float_as_uint(f);
    u = (u + 0x7fffu + ((u >> 16) & 1u)) >> 16;
    return (short)u;
}
__device__ __forceinline__ float bf2f(short s) {
    return __uint_as_float(((unsigned)(unsigned short)s) << 16);
}
__device__ __forceinline__ short f2h(float f) {
    const _Float16 h = (_Float16)f;
    union { _Float16 h; short s; } u; u.h = h; return u.s;
}
__device__ __forceinline__ f16x8 as_h(s16x8 v) {
    union { s16x8 s; f16x8 h; } u; u.s = v; return u.h;
}

__device__ __forceinline__ void gload_lds16(const void* g, void* l) {
    __builtin_amdgcn_global_load_lds(
        (const __attribute__((address_space(1))) void*)g,
        (__attribute__((address_space(3))) void*)l, 16, 0, 0);
}

// ---------------------------------------------------------------------------
// QK^T 256x256, BK=32, 8 waves, SINGLE-pass fp16 (Q and K both fp16).
// R3-proven schedule + XCD swizzle. int16 score out via LDS repack.
// Staging: [2 buf][2 arr: q,k][8192] = 64 KiB inside the 128 KiB union.
// ---------------------------------------------------------------------------
__global__ __launch_bounds__(512, 2) void qkt256(
    const short* __restrict__ qf, const short* __restrict__ kf,
    short* __restrict__ outS, int nwg)
{
    __shared__ short lds[65536];  // 128 KiB (epilogue repack needs all of it)

    const int tid = threadIdx.x;
    const int wave = tid >> 6, lane = tid & 63;
    const int flat = blockIdx.x + 8 * blockIdx.y + 64 * blockIdx.z;
    const int w = (flat & 7) * (nwg >> 3) + (flat >> 3);
    const int bm = ((w >> 3) & 7) * 256, bn = (w & 7) * 256;
    const long z = w >> 6;
    qf += z * (long)SS * DD; kf += z * (long)SS * DD;
    outS += z * (long)SS * SS;

    const int wm = (wave >> 2) * 128, wn = (wave & 3) * 64;
    const int lrow = lane & 15, lk16 = (lane >> 4) * 16;

    f32x4 acc[8][4] = {};

    auto base = [&](int buf, int arr) -> short* { return &lds[(buf * 2 + arr) * 8192]; };
    auto issue = [&](int buf, int arr, int k0) {
#pragma unroll
        for (int h = 0; h < 2; h++) {
            const int Lb = (h << 13) + (wave << 10) + (lane << 4);
            const int Ls = Lb ^ (((Lb >> 7) & 3) << 4);
            const int row = Ls >> 6, elem = (Ls & 63) >> 1;
            const short* s = arr ? kf : qf;
            const int rb = arr ? bn : bm;
            gload_lds16(s + (size_t)(rb + row) * DD + k0 + elem,
                        (char*)base(buf, arr) + Lb);
        }
    };
    auto rd = [&](int buf, int arr, int row) -> s16x8 {
        const int L = (row << 6) + lk16;
        const int Ls = L ^ (((L >> 7) & 3) << 4);
        return *(const s16x8*)((const char*)base(buf, arr) + Ls);
    };

// per tile: p0 issues k (2 loads), p1 issues q (2 loads).
// vmcnt(2)@p2-end -> k landed (gates p3's B-next reads, post-barrier);
// vmcnt(0)@p3-end -> q landed (gates next tile's A reads).
// p3: 2 A-reads + 4 B-next reads -> lgkmcnt(4) drains only the A-reads.
#define QK_TILE(T, CUR, Bc, Bn, PREF)                                            \
  {                                                                              \
    _Pragma("unroll")                                                            \
    for (int p = 0; p < 4; p++) {                                                \
      const s16x8 ah0 = rd(CUR, 0, wm + (p * 2 + 0) * 16 + lrow);                \
      const s16x8 ah1 = rd(CUR, 0, wm + (p * 2 + 1) * 16 + lrow);                \
      if (PREF && p == 0) { issue((CUR) ^ 1, 1, ((T) + 1) * 32); }               \
      if (PREF && p == 1) { issue((CUR) ^ 1, 0, ((T) + 1) * 32); }               \
      if (PREF && p == 3) {                                                      \
        __builtin_amdgcn_sched_barrier(0); /* pin A-reads before B-reads */      \
        _Pragma("unroll")                                                        \
        for (int n = 0; n < 4; n++) {                                            \
          Bn[n] = rd((CUR) ^ 1, 1, wn + n * 16 + lrow);                          \
        }                                                                        \
      }                                                                          \
      __builtin_amdgcn_s_barrier();                                              \
      if (PREF && p == 3) { asm volatile("s_waitcnt lgkmcnt(4)" ::: "memory"); } \
      else                { asm volatile("s_waitcnt lgkmcnt(0)" ::: "memory"); } \
      __builtin_amdgcn_sched_barrier(0);                                         \
      __builtin_amdgcn_s_setprio(1);                                             \
      _Pragma("unroll")                                                          \
      for (int q = 0; q < 2; q++) {                                              \
        const s16x8 af = q ? ah1 : ah0;                                          \
        _Pragma("unroll")                                                        \
        for (int n = 0; n < 4; n++) {                                            \
          acc[p * 2 + q][n] = __builtin_amdgcn_mfma_f32_16x16x32_f16(            \
              as_h(af), as_h(Bc[n]), acc[p * 2 + q][n], 0, 0, 0);                \
        }                                                                        \
      }                                                                          \
      __builtin_amdgcn_s_setprio(0);                                             \
      if (PREF && p == 2) { asm volatile("s_waitcnt vmcnt(2)" ::: "memory");     \
                            __builtin_amdgcn_sched_barrier(0); }                 \
      if (PREF && p == 3) { asm volatile("s_waitcnt vmcnt(0)" ::: "memory");     \
                            __builtin_amdgcn_sched_barrier(0); }                 \
      __builtin_amdgcn_s_barrier();                                              \
    }                                                                            \
  }

    issue(0, 1, 0); issue(0, 0, 0);
    asm volatile("s_waitcnt vmcnt(0)" ::: "memory");
    __builtin_amdgcn_s_barrier();
    s16x8 bE[4], bO[4];
#pragma unroll
    for (int n = 0; n < 4; n++) bE[n] = rd(0, 1, wn + n * 16 + lrow);

    for (int t = 0; t < 14; t += 2) {
        QK_TILE(t,     0, bE, bO, 1);
        QK_TILE(t + 1, 1, bO, bE, 1);
    }
    QK_TILE(14, 0, bE, bO, 1);
    QK_TILE(15, 1, bO, bE, 0);
#undef QK_TILE

    // int16 epilogue via LDS repack -> coalesced 16B/lane stores.
    __syncthreads();
    short* ebuf = &lds[0];  // 128 KiB = [256][256] int16
#pragma unroll
    for (int m = 0; m < 8; m++) {
#pragma unroll
        for (int n = 0; n < 4; n++) {
#pragma unroll
            for (int j = 0; j < 4; j++) {
                const int rl = wm + m * 16 + (lane >> 4) * 4 + j;
                const int cl = wn + n * 16 + lrow;
                const int pcb = (cl >> 3) ^ ((rl & 3) << 1);
                ebuf[rl * 256 + pcb * 8 + (cl & 7)] =
                    (short)__float2int_rn(acc[m][n][j] * 128.0f);
            }
        }
    }
    __syncthreads();
#pragma unroll
    for (int it = 0; it < 16; it++) {
        const int u = it * 512 + tid;
        const int R = u >> 5, cb = u & 31;
        const int pcb = cb ^ ((R & 3) << 1);
        const s16x8 val = *(const s16x8*)&ebuf[R * 256 + pcb * 8];
        *(s16x8*)&outS[(size_t)(bm + R) * SS + bn + cb * 8] = val;
    }
}

// ---------------------------------------------------------------------------
// Unified projection: grid dim3(12, 64). wsel = blockIdx.x>>2: 0=Q, 1=K
// (split-x 3-pass bf16 MFMA, fp16 output via coalescing cbuf), 2=V (1-pass,
// bf16 transposed Vt output). cbuf is unioned with As (dead after K-loop).
// 3-bit XOR LDS swizzle throughout (R8-proven).
// ---------------------------------------------------------------------------
__global__ __launch_bounds__(256, 2) void proj_all(
    const short* __restrict__ xh, const short* __restrict__ xl,
    const short* __restrict__ wt_h, const short* __restrict__ wt_l,
    const float* __restrict__ bq, const float* __restrict__ bk,
    const float* __restrict__ bv,
    short* __restrict__ qfp, short* __restrict__ kfp, short* __restrict__ vt)
{
    __shared__ short As[2][128 * 64];   // 32 KiB, reused as cbuf
    __shared__ short Bs[2][128 * 64];   // 32 KiB

    const int tid = threadIdx.x;
    const int wave = tid >> 6, lane = tid & 63;
    const int wsel = blockIdx.x >> 2;
    const int bnl = (blockIdx.x & 3) * 128;
    const int bm = blockIdx.y * 128;
    const bool lo = (wsel < 2);
    const short* B0 = wt_h + (size_t)wsel * DD * DD;
    const short* B1 = wt_l + (size_t)wsel * DD * DD;
    const float* bias = (wsel == 0) ? bq : (wsel == 1) ? bk : bv;

    f32x4 acc[4][4] = {};
    const int wm = (wave >> 1) * 64, wn = (wave & 1) * 64;
    const int lrow = lane & 15, lk = (lane >> 4) * 8;

    auto swz = [](int L) { return L ^ (((L >> 7) & 7) << 4); };

    for (int k0 = 0; k0 < DD; k0 += 64) {
        if (k0) __syncthreads();
#pragma unroll
        for (int r = 0; r < 4; r++) {
            const int L = tid * 16 + r * 4096;
            const int Ls = swz(L);
            const int row = Ls >> 7, col = (Ls & 127) >> 1;
            gload_lds16(xh + (size_t)(bm + row) * DD + k0 + col, (char*)&As[0][0] + L);
            gload_lds16(B0 + (size_t)(bnl + row) * DD + k0 + col, (char*)&Bs[0][0] + L);
            if (lo) {
                gload_lds16(xl + (size_t)(bm + row) * DD + k0 + col, (char*)&As[1][0] + L);
                gload_lds16(B1 + (size_t)(bnl + row) * DD + k0 + col, (char*)&Bs[1][0] + L);
            }
        }
        __syncthreads();

#pragma unroll
        for (int kk = 0; kk < 64; kk += 32) {
            s16x8 ah[4], bh[4], al[4], bl[4];
#pragma unroll
            for (int m = 0; m < 4; m++)
                ah[m] = *(const s16x8*)((const char*)&As[0][0] +
                        swz(((wm + m * 16 + lrow) * 64 + kk + lk) * 2));
#pragma unroll
            for (int n = 0; n < 4; n++)
                bh[n] = *(const s16x8*)((const char*)&Bs[0][0] +
                        swz(((wn + n * 16 + lrow) * 64 + kk + lk) * 2));
            if (lo) {
#pragma unroll
                for (int m = 0; m < 4; m++)
                    al[m] = *(const s16x8*)((const char*)&As[1][0] +
                            swz(((wm + m * 16 + lrow) * 64 + kk + lk) * 2));
#pragma unroll
                for (int n = 0; n < 4; n++)
                    bl[n] = *(const s16x8*)((const char*)&Bs[1][0] +
                            swz(((wn + n * 16 + lrow) * 64 + kk + lk) * 2));
            }
#pragma unroll
            for (int m = 0; m < 4; m++) {
#pragma unroll
                for (int n = 0; n < 4; n++) {
                    acc[m][n] = __builtin_amdgcn_mfma_f32_16x16x32_bf16(ah[m], bh[n], acc[m][n], 0, 0, 0);
                    if (lo) {
                        acc[m][n] = __builtin_amdgcn_mfma_f32_16x16x32_bf16(ah[m], bl[n], acc[m][n], 0, 0, 0);
                        acc[m][n] = __builtin_amdgcn_mfma_f32_16x16x32_bf16(al[m], bh[n], acc[m][n], 0, 0, 0);
                    }
                }
            }
        }
    }

    // epilogue: route through cbuf (=As) for coalesced stores
    __syncthreads();
    short* cbuf = &As[0][0];  // 32 KiB = 128*128 shorts
#pragma unroll
    for (int m = 0; m < 4; m++) {
#pragma unroll
        for (int n = 0; n < 4; n++) {
#pragma unroll
            for (int j = 0; j < 4; j++) {
                const int rl = wm + m * 16 + (lane >> 4) * 4 + j;
                const int cl = wn + n * 16 + lrow;
                const float v = acc[m][n][j] + bias[bnl + cl];
                if (wsel < 2)
                    cbuf[rl * 128 + (cl ^ ((rl & 7) << 3))] = f2h(v);
                else
                    cbuf[cl * 128 + (rl ^ ((cl & 7) << 3))] = f2bf(v);
            }
        }
    }
    __syncthreads();
    if (wsel < 2) {
        short* outp = wsel ? kfp : qfp;
#pragma unroll
        for (int it = 0; it < 8; it++) {
            const int u = it * 256 + tid;
            const int r = u >> 4, c8 = (u & 15) * 8;
            const s16x8 val = *(const s16x8*)&cbuf[r * 128 + (c8 ^ ((r & 7) << 3))];
            *(s16x8*)&outp[(size_t)(bm + r) * DD + bnl + c8] = val;
        }
    } else {
        const int b = bm >> 11, s0 = bm & 2047;
#pragma unroll
        for (int it = 0; it < 8; it++) {
            const int idx = it * 256 + tid;
            const int dd = idx >> 4, c8 = (idx & 15) * 8;
            const s16x8 val = *(const s16x8*)&cbuf[dd * 128 + (c8 ^ ((dd & 7) << 3))];
            *(s16x8*)&vt[((size_t)b << 20) + ((size_t)(bnl + dd) << 11) + s0 + c8] = val;
        }
    }
}

// ---------------------------------------------------------------------------
// PV GEMM: 64x128 tile (2 blocks/CU), 3-bit XOR swizzle (R8-proven).
// ---------------------------------------------------------------------------
__global__ __launch_bounds__(256, 2) void pv_gemm(
    const short* __restrict__ P, const short* __restrict__ vt,
    float* __restrict__ out)
{
    __shared__ short As[64 * 64];    // 8 KiB
    __shared__ short Bs[128 * 64];   // 16 KiB

    const int tid = threadIdx.x;
    const int wave = tid >> 6, lane = tid & 63;
    const int bm = blockIdx.y * 64, bn = blockIdx.x * 128;
    const long z = blockIdx.z;
    P += z * (long)SS * SS;
    vt += z << 20;
    out += z * (long)SS * DD;

    f32x4 acc[2][4] = {};
    const int wm = (wave >> 1) * 32, wn = (wave & 1) * 64;
    const int lrow = lane & 15, lk = (lane >> 4) * 8;

    auto swz = [](int L) { return L ^ (((L >> 7) & 7) << 4); };

    for (int k0 = 0; k0 < SS; k0 += 64) {
        if (k0) __syncthreads();
#pragma unroll
        for (int r = 0; r < 2; r++) {
            const int L = tid * 16 + r * 4096;
            const int Ls = swz(L);
            const int row = Ls >> 7, col = (Ls & 127) >> 1;
            gload_lds16(P + (size_t)(bm + row) * SS + k0 + col, (char*)&As[0] + L);
        }
#pragma unroll
        for (int r = 0; r < 4; r++) {
            const int L = tid * 16 + r * 4096;
            const int Ls = swz(L);
            const int row = Ls >> 7, col = (Ls & 127) >> 1;
            gload_lds16(vt + ((size_t)(bn + row) << 11) + k0 + col, (char*)&Bs[0] + L);
        }
        __syncthreads();

#pragma unroll
        for (int kk = 0; kk < 64; kk += 32) {
            s16x8 a[2], b[4];
#pragma unroll
            for (int m = 0; m < 2; m++)
                a[m] = *(const s16x8*)((const char*)&As[0] +
                       swz(((wm + m * 16 + lrow) * 64 + kk + lk) * 2));
#pragma unroll
            for (int n = 0; n < 4; n++)
                b[n] = *(const s16x8*)((const char*)&Bs[0] +
                       swz(((wn + n * 16 + lrow) * 64 + kk + lk) * 2));
#pragma unroll
            for (int m = 0; m < 2; m++)
#pragma unroll
                for (int n = 0; n < 4; n++)
                    acc[m][n] = __builtin_amdgcn_mfma_f32_16x16x32_bf16(a[m], b[n], acc[m][n], 0, 0, 0);
        }
    }

#pragma unroll
    for (int m = 0; m < 2; m++) {
#pragma unroll
        for (int n = 0; n < 4; n++) {
#pragma unroll
            for (int j = 0; j < 4; j++) {
                const int row = bm + wm + m * 16 + (lane >> 4) * 4 + j;
                const int col = bn + wn + n * 16 + lrow;
                out[(size_t)row * DD + col] = acc[m][n][j];
            }
        }
    }
}

// merged casts: blocks [0,4096) split x; [4096,7168) split/transpose W
__global__ __launch_bounds__(256) void cast_all(
    const float* __restrict__ x,
    const float* __restrict__ wq, const float* __restrict__ wk,
    const float* __restrict__ wv,
    short* __restrict__ xh, short* __restrict__ xl,
    short* __restrict__ wth, short* __restrict__ wtl)
{
    const int bid = blockIdx.x;
    if (bid < 4096) {
        const int i = bid * 256 + threadIdx.x;
        const float4 v = ((const float4*)x)[i];
        const float vv[4] = {v.x, v.y, v.z, v.w};
        s16x4 h, l;
#pragma unroll
        for (int j = 0; j < 4; j++) {
            const short hh = f2bf(vv[j]);
            h[j] = hh;
            l[j] = f2bf(vv[j] - bf2f(hh));
        }
        ((s16x4*)xh)[i] = h;
        ((s16x4*)xl)[i] = l;
    } else {
        const int t = (bid - 4096) * 256 + threadIdx.x;
        const int w = t >> 18;
        const int r = t & 262143;
        const float* src = (w == 0) ? wq : ((w == 1) ? wk : wv);
        const float v = src[r];
        const int k = r >> 9, n = r & 511;
        const short h = f2bf(v);
        const short l = f2bf(v - bf2f(h));
        const size_t dst = ((size_t)w << 18) + ((size_t)n << 9) + k;
        wth[dst] = h;
        wtl[dst] = l;
    }
}

// softmax over int16 scores (scale 1/128), bf16 P out
__global__ __launch_bounds__(256) void softmax_rows(
    const short* __restrict__ S, short* __restrict__ P)
{
    const int row = blockIdx.x;
    const long z = blockIdx.y;
    const short* s = S + z * (long)SS * SS + (long)row * SS;
    short* p = P + z * (long)SS * SS + (long)row * SS;
    const int tid = threadIdx.x;

    const s16x8 raw = ((const s16x8*)s)[tid];
    float v[8];
#pragma unroll
    for (int j = 0; j < 8; j++) v[j] = (float)(int)raw[j] * 0.0078125f;

    float m = v[0];
#pragma unroll
    for (int j = 1; j < 8; j++) m = fmaxf(m, v[j]);
#pragma unroll
    for (int off = 32; off >= 1; off >>= 1) m = fmaxf(m, __shfl_xor(m, off));
    __shared__ float redm[4], reds[4];
    if ((tid & 63) == 0) redm[tid >> 6] = m;
    __syncthreads();
    m = fmaxf(fmaxf(redm[0], redm[1]), fmaxf(redm[2], redm[3]));

    float e[8], sum = 0.f;
#pragma unroll
    for (int j = 0; j < 8; j++) { e[j] = __expf(v[j] - m); sum += e[j]; }
#pragma unroll
    for (int off = 32; off >= 1; off >>= 1) sum += __shfl_xor(sum, off);
    if ((tid & 63) == 0) reds[tid >> 6] = sum;
    __syncthreads();
    sum = reds[0] + reds[1] + reds[2] + reds[3];
    const float inv = 1.0f / sum;

    s16x8 o;
#pragma unroll
    for (int j = 0; j < 8; j++) o[j] = f2bf(e[j] * inv);
    ((s16x8*)p)[tid] = o;
}

extern "C" void kernel_launch(void* const* d_in, const int* in_sizes, int n_in,
                              void* d_out, int out_size, void* d_ws, size_t ws_size,
                              hipStream_t stream)
{
    const float* x  = (const float*)d_in[0];
    const float* Wq = (const float*)d_in[1];
    const float* Wk = (const float*)d_in[2];
    const float* Wv = (const float*)d_in[3];
    const float* bq = (const float*)d_in[4];
    const float* bk = (const float*)d_in[5];
    const float* bv = (const float*)d_in[6];
    float* out = (float*)d_out;

    const size_t MK = (size_t)BB * SS * DD;
    char* ws = (char*)d_ws;
    short* xh  = (short*)ws; ws += MK * 2;
    short* xl  = (short*)ws; ws += MK * 2;
    short* wth = (short*)ws; ws += 3ull * DD * DD * 2;
    short* wtl = (short*)ws; ws += 3ull * DD * DD * 2;
    short* qfp = (short*)ws; ws += MK * 2;
    short* kfp = (short*)ws; ws += MK * 2;
    short* vt  = (short*)ws; ws += MK * 2;
    const size_t fixed = (size_t)(ws - (char*)d_ws);

    int g = 4;
    while (g > 0 && fixed + (size_t)g * ((size_t)SS * SS * 2 + (size_t)SS * SS * 2) > ws_size)
        g >>= 1;
    if (g == 0) return;
    short* sc = (short*)ws;
    short* P  = (short*)(ws + (size_t)g * SS * SS * 2);

    cast_all<<<dim3(7168), 256, 0, stream>>>(x, Wq, Wk, Wv, xh, xl, wth, wtl);
    proj_all<<<dim3(12, 64), 256, 0, stream>>>(xh, xl, wth, wtl, bq, bk, bv,
                                               qfp, kfp, vt);

    for (int b0 = 0; b0 < BB; b0 += g) {
        const int gg = (b0 + g <= BB) ? g : (BB - b0);
        qkt256<<<dim3(8, 8, gg), 512, 0, stream>>>(
            qfp + (size_t)b0 * SS * DD, kfp + (size_t)b0 * SS * DD, sc, 64 * gg);
        softmax_rows<<<dim3(SS, gg), 256, 0, stream>>>(sc, P);
        pv_gemm<<<dim3(4, 32, gg), 256, 0, stream>>>(
            P, vt + ((size_t)b0 << 20), out + (size_t)b0 * SS * DD);
    }
}

// Round 10
// 116.584 us; speedup vs baseline: 1.5532x; 1.1420x over previous
//
#include <hip/hip_runtime.h>
#include <hip/hip_bf16.h>
#include <hip/hip_fp16.h>

#define BB 4
#define SS 2048
#define DD 512

typedef short s16x8 __attribute__((ext_vector_type(8)));
typedef short s16x4 __attribute__((ext_vector_type(4)));
typedef float f32x4 __attribute__((ext_vector_type(4)));
typedef _Float16 f16x8 __attribute__((ext_vector_type(8)));

__device__ __forceinline__ short f2h(float f) {
    const _Float16 h = (_Float16)f;
    union { _Float16 h; short s; } u; u.h = h; return u.s;
}
__device__ __forceinline__ float h2f(short s) {
    union { short s; _Float16 h; } u; u.s = s; return (float)u.h;
}
__device__ __forceinline__ f16x8 as_h(s16x8 v) {
    union { s16x8 s; f16x8 h; } u; u.s = v; return u.h;
}

__device__ __forceinline__ void gload_lds16(const void* g, void* l) {
    __builtin_amdgcn_global_load_lds(
        (const __attribute__((address_space(1))) void*)g,
        (__attribute__((address_space(3))) void*)l, 16, 0, 0);
}

// ---------------------------------------------------------------------------
// QK^T 256x256, BK=32, 8 waves, single-pass fp16 (R9-proven schedule +
// XCD swizzle). int16 score out (scale 128) via LDS repack.
// ---------------------------------------------------------------------------
__global__ __launch_bounds__(512, 2) void qkt256(
    const short* __restrict__ qf, const short* __restrict__ kf,
    short* __restrict__ outS, int nwg)
{
    __shared__ short lds[65536];  // 128 KiB (epilogue repack needs all of it)

    const int tid = threadIdx.x;
    const int wave = tid >> 6, lane = tid & 63;
    const int flat = blockIdx.x + 8 * blockIdx.y + 64 * blockIdx.z;
    const int w = (flat & 7) * (nwg >> 3) + (flat >> 3);
    const int bm = ((w >> 3) & 7) * 256, bn = (w & 7) * 256;
    const long z = w >> 6;
    qf += z * (long)SS * DD; kf += z * (long)SS * DD;
    outS += z * (long)SS * SS;

    const int wm = (wave >> 2) * 128, wn = (wave & 3) * 64;
    const int lrow = lane & 15, lk16 = (lane >> 4) * 16;

    f32x4 acc[8][4] = {};

    auto base = [&](int buf, int arr) -> short* { return &lds[(buf * 2 + arr) * 8192]; };
    auto issue = [&](int buf, int arr, int k0) {
#pragma unroll
        for (int h = 0; h < 2; h++) {
            const int Lb = (h << 13) + (wave << 10) + (lane << 4);
            const int Ls = Lb ^ (((Lb >> 7) & 3) << 4);
            const int row = Ls >> 6, elem = (Ls & 63) >> 1;
            const short* s = arr ? kf : qf;
            const int rb = arr ? bn : bm;
            gload_lds16(s + (size_t)(rb + row) * DD + k0 + elem,
                        (char*)base(buf, arr) + Lb);
        }
    };
    auto rd = [&](int buf, int arr, int row) -> s16x8 {
        const int L = (row << 6) + lk16;
        const int Ls = L ^ (((L >> 7) & 3) << 4);
        return *(const s16x8*)((const char*)base(buf, arr) + Ls);
    };

#define QK_TILE(T, CUR, Bc, Bn, PREF)                                            \
  {                                                                              \
    _Pragma("unroll")                                                            \
    for (int p = 0; p < 4; p++) {                                                \
      const s16x8 ah0 = rd(CUR, 0, wm + (p * 2 + 0) * 16 + lrow);                \
      const s16x8 ah1 = rd(CUR, 0, wm + (p * 2 + 1) * 16 + lrow);                \
      if (PREF && p == 0) { issue((CUR) ^ 1, 1, ((T) + 1) * 32); }               \
      if (PREF && p == 1) { issue((CUR) ^ 1, 0, ((T) + 1) * 32); }               \
      if (PREF && p == 3) {                                                      \
        __builtin_amdgcn_sched_barrier(0); /* pin A-reads before B-reads */      \
        _Pragma("unroll")                                                        \
        for (int n = 0; n < 4; n++) {                                            \
          Bn[n] = rd((CUR) ^ 1, 1, wn + n * 16 + lrow);                          \
        }                                                                        \
      }                                                                          \
      __builtin_amdgcn_s_barrier();                                              \
      if (PREF && p == 3) { asm volatile("s_waitcnt lgkmcnt(4)" ::: "memory"); } \
      else                { asm volatile("s_waitcnt lgkmcnt(0)" ::: "memory"); } \
      __builtin_amdgcn_sched_barrier(0);                                         \
      __builtin_amdgcn_s_setprio(1);                                             \
      _Pragma("unroll")                                                          \
      for (int q = 0; q < 2; q++) {                                              \
        const s16x8 af = q ? ah1 : ah0;                                          \
        _Pragma("unroll")                                                        \
        for (int n = 0; n < 4; n++) {                                            \
          acc[p * 2 + q][n] = __builtin_amdgcn_mfma_f32_16x16x32_f16(            \
              as_h(af), as_h(Bc[n]), acc[p * 2 + q][n], 0, 0, 0);                \
        }                                                                        \
      }                                                                          \
      __builtin_amdgcn_s_setprio(0);                                             \
      if (PREF && p == 2) { asm volatile("s_waitcnt vmcnt(2)" ::: "memory");     \
                            __builtin_amdgcn_sched_barrier(0); }                 \
      if (PREF && p == 3) { asm volatile("s_waitcnt vmcnt(0)" ::: "memory");     \
                            __builtin_amdgcn_sched_barrier(0); }                 \
      __builtin_amdgcn_s_barrier();                                              \
    }                                                                            \
  }

    issue(0, 1, 0); issue(0, 0, 0);
    asm volatile("s_waitcnt vmcnt(0)" ::: "memory");
    __builtin_amdgcn_s_barrier();
    s16x8 bE[4], bO[4];
#pragma unroll
    for (int n = 0; n < 4; n++) bE[n] = rd(0, 1, wn + n * 16 + lrow);

    for (int t = 0; t < 14; t += 2) {
        QK_TILE(t,     0, bE, bO, 1);
        QK_TILE(t + 1, 1, bO, bE, 1);
    }
    QK_TILE(14, 0, bE, bO, 1);
    QK_TILE(15, 1, bO, bE, 0);
#undef QK_TILE

    __syncthreads();
    short* ebuf = &lds[0];  // 128 KiB = [256][256] int16
#pragma unroll
    for (int m = 0; m < 8; m++) {
#pragma unroll
        for (int n = 0; n < 4; n++) {
#pragma unroll
            for (int j = 0; j < 4; j++) {
                const int rl = wm + m * 16 + (lane >> 4) * 4 + j;
                const int cl = wn + n * 16 + lrow;
                const int pcb = (cl >> 3) ^ ((rl & 3) << 1);
                ebuf[rl * 256 + pcb * 8 + (cl & 7)] =
                    (short)__float2int_rn(acc[m][n][j] * 128.0f);
            }
        }
    }
    __syncthreads();
#pragma unroll
    for (int it = 0; it < 16; it++) {
        const int u = it * 512 + tid;
        const int R = u >> 5, cb = u & 31;
        const int pcb = cb ^ ((R & 3) << 1);
        const s16x8 val = *(const s16x8*)&ebuf[R * 256 + pcb * 8];
        *(s16x8*)&outS[(size_t)(bm + R) * SS + bn + cb * 8] = val;
    }
}

// ---------------------------------------------------------------------------
// Unified projection, all-fp16: grid dim3(12, 64). wsel = blockIdx.x>>2:
// 0=Q, 1=K (2-pass: xh*W + xl*W, fp16 hi/lo x-split, single fp16 W plane),
// 2=V (1-pass xh*W, transposed fp16 Vt out). LDS 48 KiB -> 3 blocks/CU.
// 3-bit XOR LDS swizzle (R8-proven). Coalesced epilogue via cbuf (=As).
// ---------------------------------------------------------------------------
__global__ __launch_bounds__(256, 3) void proj_all(
    const short* __restrict__ xh, const short* __restrict__ xl,
    const short* __restrict__ wt,
    const float* __restrict__ bq, const float* __restrict__ bk,
    const float* __restrict__ bv,
    short* __restrict__ qfp, short* __restrict__ kfp, short* __restrict__ vt)
{
    __shared__ short As[2][128 * 64];   // 32 KiB, reused as cbuf
    __shared__ short Bs[128 * 64];      // 16 KiB

    const int tid = threadIdx.x;
    const int wave = tid >> 6, lane = tid & 63;
    const int wsel = blockIdx.x >> 2;
    const int bnl = (blockIdx.x & 3) * 128;
    const int bm = blockIdx.y * 128;
    const bool lo = (wsel < 2);
    const short* B0 = wt + (size_t)wsel * DD * DD;
    const float* bias = (wsel == 0) ? bq : (wsel == 1) ? bk : bv;

    f32x4 acc[4][4] = {};
    const int wm = (wave >> 1) * 64, wn = (wave & 1) * 64;
    const int lrow = lane & 15, lk = (lane >> 4) * 8;

    auto swz = [](int L) { return L ^ (((L >> 7) & 7) << 4); };

    for (int k0 = 0; k0 < DD; k0 += 64) {
        if (k0) __syncthreads();
#pragma unroll
        for (int r = 0; r < 4; r++) {
            const int L = tid * 16 + r * 4096;
            const int Ls = swz(L);
            const int row = Ls >> 7, col = (Ls & 127) >> 1;
            gload_lds16(xh + (size_t)(bm + row) * DD + k0 + col, (char*)&As[0][0] + L);
            gload_lds16(B0 + (size_t)(bnl + row) * DD + k0 + col, (char*)&Bs[0] + L);
            if (lo)
                gload_lds16(xl + (size_t)(bm + row) * DD + k0 + col, (char*)&As[1][0] + L);
        }
        __syncthreads();

#pragma unroll
        for (int kk = 0; kk < 64; kk += 32) {
            s16x8 ah[4], bh[4], al[4];
#pragma unroll
            for (int m = 0; m < 4; m++)
                ah[m] = *(const s16x8*)((const char*)&As[0][0] +
                        swz(((wm + m * 16 + lrow) * 64 + kk + lk) * 2));
#pragma unroll
            for (int n = 0; n < 4; n++)
                bh[n] = *(const s16x8*)((const char*)&Bs[0] +
                        swz(((wn + n * 16 + lrow) * 64 + kk + lk) * 2));
            if (lo) {
#pragma unroll
                for (int m = 0; m < 4; m++)
                    al[m] = *(const s16x8*)((const char*)&As[1][0] +
                            swz(((wm + m * 16 + lrow) * 64 + kk + lk) * 2));
            }
#pragma unroll
            for (int m = 0; m < 4; m++) {
#pragma unroll
                for (int n = 0; n < 4; n++) {
                    acc[m][n] = __builtin_amdgcn_mfma_f32_16x16x32_f16(
                        as_h(ah[m]), as_h(bh[n]), acc[m][n], 0, 0, 0);
                    if (lo)
                        acc[m][n] = __builtin_amdgcn_mfma_f32_16x16x32_f16(
                            as_h(al[m]), as_h(bh[n]), acc[m][n], 0, 0, 0);
                }
            }
        }
    }

    // epilogue through cbuf (=As) for coalesced 16B stores
    __syncthreads();
    short* cbuf = &As[0][0];  // 32 KiB = 128*128 shorts
#pragma unroll
    for (int m = 0; m < 4; m++) {
#pragma unroll
        for (int n = 0; n < 4; n++) {
#pragma unroll
            for (int j = 0; j < 4; j++) {
                const int rl = wm + m * 16 + (lane >> 4) * 4 + j;
                const int cl = wn + n * 16 + lrow;
                const float v = acc[m][n][j] + bias[bnl + cl];
                if (wsel < 2)
                    cbuf[rl * 128 + (cl ^ ((rl & 7) << 3))] = f2h(v);
                else
                    cbuf[cl * 128 + (rl ^ ((cl & 7) << 3))] = f2h(v);
            }
        }
    }
    __syncthreads();
    if (wsel < 2) {
        short* outp = wsel ? kfp : qfp;
#pragma unroll
        for (int it = 0; it < 8; it++) {
            const int u = it * 256 + tid;
            const int r = u >> 4, c8 = (u & 15) * 8;
            const s16x8 val = *(const s16x8*)&cbuf[r * 128 + (c8 ^ ((r & 7) << 3))];
            *(s16x8*)&outp[(size_t)(bm + r) * DD + bnl + c8] = val;
        }
    } else {
        const int b = bm >> 11, s0 = bm & 2047;
#pragma unroll
        for (int it = 0; it < 8; it++) {
            const int idx = it * 256 + tid;
            const int dd = idx >> 4, c8 = (idx & 15) * 8;
            const s16x8 val = *(const s16x8*)&cbuf[dd * 128 + (c8 ^ ((dd & 7) << 3))];
            *(s16x8*)&vt[((size_t)b << 20) + ((size_t)(bnl + dd) << 11) + s0 + c8] = val;
        }
    }
}

// ---------------------------------------------------------------------------
// PV GEMM fp16: 64x128 tile (2+ blocks/CU), 3-bit XOR swizzle (R8-proven).
// ---------------------------------------------------------------------------
__global__ __launch_bounds__(256, 2) void pv_gemm(
    const short* __restrict__ P, const short* __restrict__ vt,
    float* __restrict__ out)
{
    __shared__ short As[64 * 64];    // 8 KiB
    __shared__ short Bs[128 * 64];   // 16 KiB

    const int tid = threadIdx.x;
    const int wave = tid >> 6, lane = tid & 63;
    const int bm = blockIdx.y * 64, bn = blockIdx.x * 128;
    const long z = blockIdx.z;
    P += z * (long)SS * SS;
    vt += z << 20;
    out += z * (long)SS * DD;

    f32x4 acc[2][4] = {};
    const int wm = (wave >> 1) * 32, wn = (wave & 1) * 64;
    const int lrow = lane & 15, lk = (lane >> 4) * 8;

    auto swz = [](int L) { return L ^ (((L >> 7) & 7) << 4); };

    for (int k0 = 0; k0 < SS; k0 += 64) {
        if (k0) __syncthreads();
#pragma unroll
        for (int r = 0; r < 2; r++) {
            const int L = tid * 16 + r * 4096;
            const int Ls = swz(L);
            const int row = Ls >> 7, col = (Ls & 127) >> 1;
            gload_lds16(P + (size_t)(bm + row) * SS + k0 + col, (char*)&As[0] + L);
        }
#pragma unroll
        for (int r = 0; r < 4; r++) {
            const int L = tid * 16 + r * 4096;
            const int Ls = swz(L);
            const int row = Ls >> 7, col = (Ls & 127) >> 1;
            gload_lds16(vt + ((size_t)(bn + row) << 11) + k0 + col, (char*)&Bs[0] + L);
        }
        __syncthreads();

#pragma unroll
        for (int kk = 0; kk < 64; kk += 32) {
            s16x8 a[2], b[4];
#pragma unroll
            for (int m = 0; m < 2; m++)
                a[m] = *(const s16x8*)((const char*)&As[0] +
                       swz(((wm + m * 16 + lrow) * 64 + kk + lk) * 2));
#pragma unroll
            for (int n = 0; n < 4; n++)
                b[n] = *(const s16x8*)((const char*)&Bs[0] +
                       swz(((wn + n * 16 + lrow) * 64 + kk + lk) * 2));
#pragma unroll
            for (int m = 0; m < 2; m++)
#pragma unroll
                for (int n = 0; n < 4; n++)
                    acc[m][n] = __builtin_amdgcn_mfma_f32_16x16x32_f16(
                        as_h(a[m]), as_h(b[n]), acc[m][n], 0, 0, 0);
        }
    }

#pragma unroll
    for (int m = 0; m < 2; m++) {
#pragma unroll
        for (int n = 0; n < 4; n++) {
#pragma unroll
            for (int j = 0; j < 4; j++) {
                const int row = bm + wm + m * 16 + (lane >> 4) * 4 + j;
                const int col = bn + wn + n * 16 + lrow;
                out[(size_t)row * DD + col] = acc[m][n][j];
            }
        }
    }
}

// merged casts: blocks [0,4096) split x into fp16 hi/lo;
// [4096,7168) transpose W into single fp16 plane.
__global__ __launch_bounds__(256) void cast_all(
    const float* __restrict__ x,
    const float* __restrict__ wq, const float* __restrict__ wk,
    const float* __restrict__ wv,
    short* __restrict__ xh, short* __restrict__ xl,
    short* __restrict__ wt)
{
    const int bid = blockIdx.x;
    if (bid < 4096) {
        const int i = bid * 256 + threadIdx.x;
        const float4 v = ((const float4*)x)[i];
        const float vv[4] = {v.x, v.y, v.z, v.w};
        s16x4 h, l;
#pragma unroll
        for (int j = 0; j < 4; j++) {
            const short hh = f2h(vv[j]);
            h[j] = hh;
            l[j] = f2h(vv[j] - h2f(hh));
        }
        ((s16x4*)xh)[i] = h;
        ((s16x4*)xl)[i] = l;
    } else {
        const int t = (bid - 4096) * 256 + threadIdx.x;
        const int w = t >> 18;
        const int r = t & 262143;
        const float* src = (w == 0) ? wq : ((w == 1) ? wk : wv);
        const float v = src[r];
        const int k = r >> 9, n = r & 511;
        wt[((size_t)w << 18) + ((size_t)n << 9) + k] = f2h(v);
    }
}

// softmax over int16 scores (scale 1/128), fp16 P out
__global__ __launch_bounds__(256) void softmax_rows(
    const short* __restrict__ S, short* __restrict__ P)
{
    const int row = blockIdx.x;
    const long z = blockIdx.y;
    const short* s = S + z * (long)SS * SS + (long)row * SS;
    short* p = P + z * (long)SS * SS + (long)row * SS;
    const int tid = threadIdx.x;

    const s16x8 raw = ((const s16x8*)s)[tid];
    float v[8];
#pragma unroll
    for (int j = 0; j < 8; j++) v[j] = (float)(int)raw[j] * 0.0078125f;

    float m = v[0];
#pragma unroll
    for (int j = 1; j < 8; j++) m = fmaxf(m, v[j]);
#pragma unroll
    for (int off = 32; off >= 1; off >>= 1) m = fmaxf(m, __shfl_xor(m, off));
    __shared__ float redm[4], reds[4];
    if ((tid & 63) == 0) redm[tid >> 6] = m;
    __syncthreads();
    m = fmaxf(fmaxf(redm[0], redm[1]), fmaxf(redm[2], redm[3]));

    float e[8], sum = 0.f;
#pragma unroll
    for (int j = 0; j < 8; j++) { e[j] = __expf(v[j] - m); sum += e[j]; }
#pragma unroll
    for (int off = 32; off >= 1; off >>= 1) sum += __shfl_xor(sum, off);
    if ((tid & 63) == 0) reds[tid >> 6] = sum;
    __syncthreads();
    sum = reds[0] + reds[1] + reds[2] + reds[3];
    const float inv = 1.0f / sum;

    s16x8 o;
#pragma unroll
    for (int j = 0; j < 8; j++) o[j] = f2h(e[j] * inv);
    ((s16x8*)p)[tid] = o;
}

extern "C" void kernel_launch(void* const* d_in, const int* in_sizes, int n_in,
                              void* d_out, int out_size, void* d_ws, size_t ws_size,
                              hipStream_t stream)
{
    const float* x  = (const float*)d_in[0];
    const float* Wq = (const float*)d_in[1];
    const float* Wk = (const float*)d_in[2];
    const float* Wv = (const float*)d_in[3];
    const float* bq = (const float*)d_in[4];
    const float* bk = (const float*)d_in[5];
    const float* bv = (const float*)d_in[6];
    float* out = (float*)d_out;

    const size_t MK = (size_t)BB * SS * DD;
    char* ws = (char*)d_ws;
    short* xh  = (short*)ws; ws += MK * 2;
    short* xl  = (short*)ws; ws += MK * 2;
    short* wt  = (short*)ws; ws += 3ull * DD * DD * 2;
    short* qfp = (short*)ws; ws += MK * 2;
    short* kfp = (short*)ws; ws += MK * 2;
    short* vt  = (short*)ws; ws += MK * 2;
    const size_t fixed = (size_t)(ws - (char*)d_ws);

    int g = 4;
    while (g > 0 && fixed + (size_t)g * ((size_t)SS * SS * 2 + (size_t)SS * SS * 2) > ws_size)
        g >>= 1;
    if (g == 0) return;
    short* sc = (short*)ws;
    short* P  = (short*)(ws + (size_t)g * SS * SS * 2);

    cast_all<<<dim3(7168), 256, 0, stream>>>(x, Wq, Wk, Wv, xh, xl, wt);
    proj_all<<<dim3(12, 64), 256, 0, stream>>>(xh, xl, wt, bq, bk, bv,
                                               qfp, kfp, vt);

    for (int b0 = 0; b0 < BB; b0 += g) {
        const int gg = (b0 + g <= BB) ? g : (BB - b0);
        qkt256<<<dim3(8, 8, gg), 512, 0, stream>>>(
            qfp + (size_t)b0 * SS * DD, kfp + (size_t)b0 * SS * DD, sc, 64 * gg);
        softmax_rows<<<dim3(SS, gg), 256, 0, stream>>>(sc, P);
        pv_gemm<<<dim3(4, 32, gg), 256, 0, stream>>>(
            P, vt + ((size_t)b0 << 20), out + (size_t)b0 * SS * DD);
    }
}